// Round 2
// baseline (2200.870 us; speedup 1.0000x reference)
//
#include <hip/hip_runtime.h>
#include <hip/hip_bf16.h>

#define HDIM 128
#define FIN  32

typedef __hip_bfloat16 bf16t;

__device__ __forceinline__ float reluf(float x) { return x > 0.f ? x : 0.f; }

__device__ __forceinline__ unsigned short f2bf(float f) {
    unsigned int b = __float_as_uint(f);
    b += 0x7FFFu + ((b >> 16) & 1u);       // round-to-nearest-even
    return (unsigned short)(b >> 16);
}
__device__ __forceinline__ float bf2f(unsigned short u) {
    return __uint_as_float(((unsigned int)u) << 16);
}

__device__ __forceinline__ float4 ld4(const float* p) { return *(const float4*)p; }
__device__ __forceinline__ float4 ld4(const bf16t* p) {
    ushort4 u = *(const ushort4*)p;
    return make_float4(bf2f(u.x), bf2f(u.y), bf2f(u.z), bf2f(u.w));
}
__device__ __forceinline__ void st4(float* p, float4 v) { *(float4*)p = v; }
__device__ __forceinline__ void st4(bf16t* p, float4 v) {
    ushort4 u;
    u.x = f2bf(v.x); u.y = f2bf(v.y); u.z = f2bf(v.z); u.w = f2bf(v.w);
    *(ushort4*)p = u;
}

// ---------------------------------------------------------------------------
// Encoder: h = relu(x @ W + b); x:[N,32], W:[32,128].  LDS 25.6 KB.
// ---------------------------------------------------------------------------
template<typename T>
__global__ __launch_bounds__(256) void enc_kernel(
    const float* __restrict__ x, const float* __restrict__ W,
    const float* __restrict__ b, T* __restrict__ h, int N)
{
    __shared__ float w_s[FIN * HDIM];
    __shared__ float x_s[64 * 36];
    const int tid  = threadIdx.x;
    const int row0 = blockIdx.x * 64;

    #pragma unroll
    for (int i = 0; i < 4; ++i) {
        int f = tid + i * 256;              // float4 idx in 32x128
        int r = f >> 5, c4 = f & 31;
        *(float4*)&w_s[r * HDIM + c4 * 4] =
            *(const float4*)&W[(size_t)r * HDIM + c4 * 4];
    }
    #pragma unroll
    for (int i = 0; i < 2; ++i) {
        int f = tid + i * 256;              // float4 idx in 64x32
        int r = f >> 3, c4 = f & 7;
        float4 v = make_float4(0.f, 0.f, 0.f, 0.f);
        if (row0 + r < N)
            v = *(const float4*)&x[(size_t)(row0 + r) * FIN + c4 * 4];
        *(float4*)&x_s[r * 36 + c4 * 4] = v;
    }
    __syncthreads();

    const int tr = tid >> 4, tc = tid & 15, trow = tr * 4;
    float acc[4][8] = {};
    #pragma unroll
    for (int k = 0; k < FIN; ++k) {
        float av[4];
        #pragma unroll
        for (int r = 0; r < 4; ++r) av[r] = x_s[(trow + r) * 36 + k];
        float4 w0 = *(float4*)&w_s[k * HDIM + tc * 8];
        float4 w1 = *(float4*)&w_s[k * HDIM + tc * 8 + 4];
        float wv[8] = {w0.x, w0.y, w0.z, w0.w, w1.x, w1.y, w1.z, w1.w};
        #pragma unroll
        for (int r = 0; r < 4; ++r)
            #pragma unroll
            for (int c = 0; c < 8; ++c)
                acc[r][c] += av[r] * wv[c];
    }

    float4 b0 = *(const float4*)&b[tc * 8];
    float4 b1 = *(const float4*)&b[tc * 8 + 4];
    float bv[8] = {b0.x, b0.y, b0.z, b0.w, b1.x, b1.y, b1.z, b1.w};
    #pragma unroll
    for (int r = 0; r < 4; ++r) {
        int row = row0 + trow + r;
        if (row < N) {
            float4 o0 = make_float4(reluf(acc[r][0] + bv[0]), reluf(acc[r][1] + bv[1]),
                                    reluf(acc[r][2] + bv[2]), reluf(acc[r][3] + bv[3]));
            float4 o1 = make_float4(reluf(acc[r][4] + bv[4]), reluf(acc[r][5] + bv[5]),
                                    reluf(acc[r][6] + bv[6]), reluf(acc[r][7] + bv[7]));
            st4(&h[(size_t)row * HDIM + tc * 8],     o0);
            st4(&h[(size_t)row * HDIM + tc * 8 + 4], o1);
        }
    }
}

// ---------------------------------------------------------------------------
// Fused level-0: msg[dst[e]] += relu(x_col[src[e]] @ W0 + b0)
// One wave per edge (grid-stride). Avoids materializing h_col (256 MB).
// ---------------------------------------------------------------------------
__global__ __launch_bounds__(256) void enc_scatter_kernel(
    const float* __restrict__ x, const int* __restrict__ src,
    const int* __restrict__ dst, const float* __restrict__ W,
    const float* __restrict__ b, float* __restrict__ msg, int E)
{
    __shared__ float w_s[FIN * HDIM];   // 16 KB
    for (int i = threadIdx.x; i < FIN * HDIM / 4; i += 256)
        ((float4*)w_s)[i] = ((const float4*)W)[i];
    __syncthreads();

    const int lane = threadIdx.x & 63;
    const int wid0 = blockIdx.x * 4 + (threadIdx.x >> 6);
    const int nw   = gridDim.x * 4;
    const float b0 = b[lane], b1 = b[64 + lane];

    for (int e = wid0; e < E; e += nw) {
        int s = src[e], d = dst[e];
        float xv = x[(size_t)s * FIN + (lane & 31)];
        float a0 = 0.f, a1 = 0.f;
        #pragma unroll
        for (int k = 0; k < FIN; ++k) {
            float xk = __shfl(xv, k, 64);
            a0 += xk * w_s[k * HDIM + lane];
            a1 += xk * w_s[k * HDIM + 64 + lane];
        }
        a0 = reluf(a0 + b0);
        a1 = reluf(a1 + b1);
        atomicAdd(&msg[(size_t)d * HDIM + lane],      a0);
        atomicAdd(&msg[(size_t)d * HDIM + 64 + lane], a1);
    }
}

// ---------------------------------------------------------------------------
// Segment-sum: msg[dst[e]] += h_src[src[e]]  (32 lanes per edge)
// ---------------------------------------------------------------------------
template<typename T>
__global__ __launch_bounds__(256) void scatter_kernel(
    const T* __restrict__ hsrc, const int* __restrict__ src,
    const int* __restrict__ dst, float* __restrict__ msg, int E)
{
    int t = blockIdx.x * 256 + threadIdx.x;
    int e = t >> 5;
    if (e >= E) return;
    int c = t & 31;
    int s = src[e], d = dst[e];
    float4 v = ld4(&hsrc[(size_t)s * HDIM + c * 4]);
    float* p = &msg[(size_t)d * HDIM + c * 4];
    atomicAdd(p + 0, v.x);
    atomicAdd(p + 1, v.y);
    atomicAdd(p + 2, v.z);
    atomicAdd(p + 3, v.w);
}

// ---------------------------------------------------------------------------
// Combine (fused 2-layer MLP, in-place on hd):
//   z1 = relu([hd | msg] @ W1 + b1); hd = relu(z1 @ W2 + b2)
// LDS 50.2 KB (z-buffer aliased over a-tile; 32-row weight chunks).
// ---------------------------------------------------------------------------
template<typename TH>
__global__ __launch_bounds__(256) void combine_kernel(
    TH* __restrict__ hd, const float* __restrict__ msg,
    const float* __restrict__ W1, const float* __restrict__ b1,
    const float* __restrict__ W2, const float* __restrict__ b2, int N)
{
    __shared__ float smem[12544];        // 50,176 B
    float* z_s = smem;                   // 64x128, stride 132 (GEMM2 phase)
    float* a_s = smem + 4096;            // 64x64,  stride 68  (GEMM1 phase)
    float* w_s = smem + 8448;            // 32x128

    const int tid  = threadIdx.x;
    const int row0 = blockIdx.x * 64;
    const int tr = tid >> 4, tc = tid & 15, trow = tr * 4;

    float acc[4][8] = {};

    // ---- GEMM1: K=256 over [hd | msg], 4 halves x 2 weight-subchunks ----
    for (int half = 0; half < 4; ++half) {
        __syncthreads();                 // prior reads of a_s/w_s done
        const int koff = (half & 1) * 64;
        #pragma unroll
        for (int i = 0; i < 4; ++i) {
            int f = tid + i * 256;       // float4 idx in 64x64
            int r = f >> 4, c4 = f & 15;
            float4 v = make_float4(0.f, 0.f, 0.f, 0.f);
            if (row0 + r < N) {
                if (half < 2) v = ld4(&hd [(size_t)(row0 + r) * HDIM + koff + c4 * 4]);
                else          v = ld4(&msg[(size_t)(row0 + r) * HDIM + koff + c4 * 4]);
            }
            *(float4*)&a_s[r * 68 + c4 * 4] = v;
        }
        #pragma unroll
        for (int sub = 0; sub < 2; ++sub) {
            if (sub) __syncthreads();    // protect w_s from previous k-loop
            #pragma unroll
            for (int i = 0; i < 4; ++i) {
                int f = tid + i * 256;   // float4 idx in 32x128
                int r = f >> 5, c4 = f & 31;
                *(float4*)&w_s[r * HDIM + c4 * 4] =
                    *(const float4*)&W1[(size_t)(half * 64 + sub * 32 + r) * HDIM + c4 * 4];
            }
            __syncthreads();             // a_s + w_s visible
            #pragma unroll 2
            for (int k = 0; k < 32; ++k) {
                float av[4];
                #pragma unroll
                for (int r = 0; r < 4; ++r)
                    av[r] = a_s[(trow + r) * 68 + sub * 32 + k];
                float4 w0 = *(float4*)&w_s[k * HDIM + tc * 8];
                float4 w1 = *(float4*)&w_s[k * HDIM + tc * 8 + 4];
                float wv[8] = {w0.x, w0.y, w0.z, w0.w, w1.x, w1.y, w1.z, w1.w};
                #pragma unroll
                for (int r = 0; r < 4; ++r)
                    #pragma unroll
                    for (int c = 0; c < 8; ++c)
                        acc[r][c] += av[r] * wv[c];
            }
        }
    }

    __syncthreads();                     // GEMM1 reads complete; z region free

    // z1 = relu(acc + b1) -> z_s
    {
        float4 ba = *(const float4*)&b1[tc * 8];
        float4 bb = *(const float4*)&b1[tc * 8 + 4];
        float bv[8] = {ba.x, ba.y, ba.z, ba.w, bb.x, bb.y, bb.z, bb.w};
        #pragma unroll
        for (int r = 0; r < 4; ++r) {
            float4 z0 = make_float4(reluf(acc[r][0] + bv[0]), reluf(acc[r][1] + bv[1]),
                                    reluf(acc[r][2] + bv[2]), reluf(acc[r][3] + bv[3]));
            float4 z1 = make_float4(reluf(acc[r][4] + bv[4]), reluf(acc[r][5] + bv[5]),
                                    reluf(acc[r][6] + bv[6]), reluf(acc[r][7] + bv[7]));
            *(float4*)&z_s[(trow + r) * 132 + tc * 8]     = z0;
            *(float4*)&z_s[(trow + r) * 132 + tc * 8 + 4] = z1;
            #pragma unroll
            for (int c = 0; c < 8; ++c) acc[r][c] = 0.f;
        }
    }

    // ---- GEMM2: K=128 over z1, 4 weight chunks of 32 rows ----
    for (int kc = 0; kc < 4; ++kc) {
        if (kc) __syncthreads();
        #pragma unroll
        for (int i = 0; i < 4; ++i) {
            int f = tid + i * 256;
            int r = f >> 5, c4 = f & 31;
            *(float4*)&w_s[r * HDIM + c4 * 4] =
                *(const float4*)&W2[(size_t)(kc * 32 + r) * HDIM + c4 * 4];
        }
        __syncthreads();                 // z_s + w_s visible
        #pragma unroll 2
        for (int k = 0; k < 32; ++k) {
            float av[4];
            #pragma unroll
            for (int r = 0; r < 4; ++r)
                av[r] = z_s[(trow + r) * 132 + kc * 32 + k];
            float4 w0 = *(float4*)&w_s[k * HDIM + tc * 8];
            float4 w1 = *(float4*)&w_s[k * HDIM + tc * 8 + 4];
            float wv[8] = {w0.x, w0.y, w0.z, w0.w, w1.x, w1.y, w1.z, w1.w};
            #pragma unroll
            for (int r = 0; r < 4; ++r)
                #pragma unroll
                for (int c = 0; c < 8; ++c)
                    acc[r][c] += av[r] * wv[c];
        }
    }

    float4 ba = *(const float4*)&b2[tc * 8];
    float4 bb = *(const float4*)&b2[tc * 8 + 4];
    float bv[8] = {ba.x, ba.y, ba.z, ba.w, bb.x, bb.y, bb.z, bb.w};
    #pragma unroll
    for (int r = 0; r < 4; ++r) {
        int row = row0 + trow + r;
        if (row < N) {
            float4 o0 = make_float4(reluf(acc[r][0] + bv[0]), reluf(acc[r][1] + bv[1]),
                                    reluf(acc[r][2] + bv[2]), reluf(acc[r][3] + bv[3]));
            float4 o1 = make_float4(reluf(acc[r][4] + bv[4]), reluf(acc[r][5] + bv[5]),
                                    reluf(acc[r][6] + bv[6]), reluf(acc[r][7] + bv[7]));
            st4(&hd[(size_t)row * HDIM + tc * 8],     o0);
            st4(&hd[(size_t)row * HDIM + tc * 8 + 4], o1);
        }
    }
}

// ---------------------------------------------------------------------------
// out = relu(in @ W + b), in:[N,128], W:[128,128].  LDS 50.2 KB.
// ---------------------------------------------------------------------------
template<typename TH>
__global__ __launch_bounds__(256) void mlp128_kernel(
    const TH* __restrict__ in, const float* __restrict__ W,
    const float* __restrict__ b, float* __restrict__ out, int N)
{
    __shared__ float smem[12544];
    float* a_s = smem;                   // 64x128 stride 132
    float* w_s = smem + 8448;            // 32x128

    const int tid  = threadIdx.x;
    const int row0 = blockIdx.x * 64;
    const int tr = tid >> 4, tc = tid & 15, trow = tr * 4;

    #pragma unroll
    for (int i = 0; i < 8; ++i) {
        int f = tid + i * 256;           // float4 idx in 64x128
        int r = f >> 5, c4 = f & 31;
        float4 v = make_float4(0.f, 0.f, 0.f, 0.f);
        if (row0 + r < N)
            v = ld4(&in[(size_t)(row0 + r) * HDIM + c4 * 4]);
        *(float4*)&a_s[r * 132 + c4 * 4] = v;
    }

    float acc[4][8] = {};
    for (int kc = 0; kc < 4; ++kc) {
        if (kc) __syncthreads();
        #pragma unroll
        for (int i = 0; i < 4; ++i) {
            int f = tid + i * 256;
            int r = f >> 5, c4 = f & 31;
            *(float4*)&w_s[r * HDIM + c4 * 4] =
                *(const float4*)&W[(size_t)(kc * 32 + r) * HDIM + c4 * 4];
        }
        __syncthreads();                 // kc==0: also makes a_s visible
        #pragma unroll 2
        for (int k = 0; k < 32; ++k) {
            float av[4];
            #pragma unroll
            for (int r = 0; r < 4; ++r)
                av[r] = a_s[(trow + r) * 132 + kc * 32 + k];
            float4 w0 = *(float4*)&w_s[k * HDIM + tc * 8];
            float4 w1 = *(float4*)&w_s[k * HDIM + tc * 8 + 4];
            float wv[8] = {w0.x, w0.y, w0.z, w0.w, w1.x, w1.y, w1.z, w1.w};
            #pragma unroll
            for (int r = 0; r < 4; ++r)
                #pragma unroll
                for (int c = 0; c < 8; ++c)
                    acc[r][c] += av[r] * wv[c];
        }
    }

    float4 ba = *(const float4*)&b[tc * 8];
    float4 bb = *(const float4*)&b[tc * 8 + 4];
    float bv[8] = {ba.x, ba.y, ba.z, ba.w, bb.x, bb.y, bb.z, bb.w};
    #pragma unroll
    for (int r = 0; r < 4; ++r) {
        int row = row0 + trow + r;
        if (row < N) {
            float4 o0 = make_float4(reluf(acc[r][0] + bv[0]), reluf(acc[r][1] + bv[1]),
                                    reluf(acc[r][2] + bv[2]), reluf(acc[r][3] + bv[3]));
            float4 o1 = make_float4(reluf(acc[r][4] + bv[4]), reluf(acc[r][5] + bv[5]),
                                    reluf(acc[r][6] + bv[6]), reluf(acc[r][7] + bv[7]));
            *(float4*)&out[(size_t)row * HDIM + tc * 8]     = o0;
            *(float4*)&out[(size_t)row * HDIM + tc * 8 + 4] = o1;
        }
    }
}

// out[row] = t1[row,:] . w + b
__global__ __launch_bounds__(256) void rowdot_kernel(
    const float* __restrict__ t1, const float* __restrict__ w,
    const float* __restrict__ b, float* __restrict__ out, int N)
{
    __shared__ float w_s[HDIM];
    if (threadIdx.x < 32)
        *(float4*)&w_s[threadIdx.x * 4] = *(const float4*)&w[threadIdx.x * 4];
    __syncthreads();
    int row = blockIdx.x * 256 + threadIdx.x;
    if (row >= N) return;
    float acc = 0.f;
    #pragma unroll
    for (int k4 = 0; k4 < 32; ++k4) {
        float4 v = *(const float4*)&t1[(size_t)row * HDIM + k4 * 4];
        acc += v.x * w_s[k4 * 4] + v.y * w_s[k4 * 4 + 1]
             + v.z * w_s[k4 * 4 + 2] + v.w * w_s[k4 * 4 + 3];
    }
    out[row] = acc + b[0];
}

// Diagnostic: encodes ws_size (MB) into d_out[0] if workspace is too small.
__global__ __launch_bounds__(256) void sentinel_kernel(float* out, int n, float val)
{
    int i = blockIdx.x * 256 + threadIdx.x;
    if (i < n) out[i] = (i == 0) ? val : 0.f;
}

// ---------------------------------------------------------------------------
template<typename TH>
static void run_all(
    const float* x_col, const float* x_filt, const float* x_pred,
    const float* x_scan, const float* x_join, const float* x_enc,
    const float* W_enc, const float* b_enc,
    const float* W1t, const float* b1t, const float* W2t, const float* b2t,
    const float* Wf1, const float* bf1, const float* Wf2, const float* bf2,
    const int* src_cf, const int* dst_cf, const int* src_fp, const int* dst_fp,
    const int* src_ps, const int* dst_ps, const int* src_sj, const int* dst_sj,
    const int* src_je, const int* dst_je,
    int N_FILT, int N_PRED, int N_SCAN, int N_JOIN, int N_ENC,
    int E_CF, int E_FP, int E_PS, int E_SJ, int E_JE,
    float* msg, TH* hreg, TH* preg, float* d_out, hipStream_t stream)
{
    const dim3 blk(256);
    TH* h_filt = hreg;                                   // [N_FILT,128]
    TH* h_pred = preg;                                   // [N_PRED,128]
    TH* h_scan = hreg;                                   // alias after h_filt dies
    TH* h_join = hreg + (size_t)N_SCAN * HDIM;
    TH* h_enc  = hreg + (size_t)(N_SCAN + N_JOIN) * HDIM;
    float* t1  = msg;                                    // alias after last scatter

    // level 0: column -> filter  (encoder fused into scatter; no h_col buffer)
    enc_kernel<TH><<<dim3((N_FILT + 63) / 64), blk, 0, stream>>>(
        x_filt, W_enc + 1 * FIN * HDIM, b_enc + 1 * HDIM, h_filt, N_FILT);
    hipMemsetAsync(msg, 0, (size_t)N_FILT * HDIM * sizeof(float), stream);
    enc_scatter_kernel<<<dim3(4096), blk, 0, stream>>>(
        x_col, src_cf, dst_cf, W_enc, b_enc, msg, E_CF);
    combine_kernel<TH><<<dim3((N_FILT + 63) / 64), blk, 0, stream>>>(
        h_filt, msg, W1t, b1t, W2t, b2t, N_FILT);

    // level 1: filter -> pred
    enc_kernel<TH><<<dim3((N_PRED + 63) / 64), blk, 0, stream>>>(
        x_pred, W_enc + 2 * FIN * HDIM, b_enc + 2 * HDIM, h_pred, N_PRED);
    hipMemsetAsync(msg, 0, (size_t)N_PRED * HDIM * sizeof(float), stream);
    scatter_kernel<TH><<<dim3((E_FP * 32 + 255) / 256), blk, 0, stream>>>(
        h_filt, src_fp, dst_fp, msg, E_FP);
    combine_kernel<TH><<<dim3((N_PRED + 63) / 64), blk, 0, stream>>>(
        h_pred, msg, W1t + 1 * 2 * HDIM * HDIM, b1t + 1 * HDIM,
        W2t + 1 * HDIM * HDIM, b2t + 1 * HDIM, N_PRED);

    // level 2: pred -> scan   (h_scan reuses dead h_filt region)
    enc_kernel<TH><<<dim3((N_SCAN + 63) / 64), blk, 0, stream>>>(
        x_scan, W_enc + 3 * FIN * HDIM, b_enc + 3 * HDIM, h_scan, N_SCAN);
    hipMemsetAsync(msg, 0, (size_t)N_SCAN * HDIM * sizeof(float), stream);
    scatter_kernel<TH><<<dim3((E_PS * 32 + 255) / 256), blk, 0, stream>>>(
        h_pred, src_ps, dst_ps, msg, E_PS);
    combine_kernel<TH><<<dim3((N_SCAN + 63) / 64), blk, 0, stream>>>(
        h_scan, msg, W1t + 2 * 2 * HDIM * HDIM, b1t + 2 * HDIM,
        W2t + 2 * HDIM * HDIM, b2t + 2 * HDIM, N_SCAN);

    // level 3: scan -> join
    enc_kernel<TH><<<dim3((N_JOIN + 63) / 64), blk, 0, stream>>>(
        x_join, W_enc + 4 * FIN * HDIM, b_enc + 4 * HDIM, h_join, N_JOIN);
    hipMemsetAsync(msg, 0, (size_t)N_JOIN * HDIM * sizeof(float), stream);
    scatter_kernel<TH><<<dim3((E_SJ * 32 + 255) / 256), blk, 0, stream>>>(
        h_scan, src_sj, dst_sj, msg, E_SJ);
    combine_kernel<TH><<<dim3((N_JOIN + 63) / 64), blk, 0, stream>>>(
        h_join, msg, W1t + 3 * 2 * HDIM * HDIM, b1t + 3 * HDIM,
        W2t + 3 * HDIM * HDIM, b2t + 3 * HDIM, N_JOIN);

    // level 4: join -> encode
    enc_kernel<TH><<<dim3((N_ENC + 63) / 64), blk, 0, stream>>>(
        x_enc, W_enc + 5 * FIN * HDIM, b_enc + 5 * HDIM, h_enc, N_ENC);
    hipMemsetAsync(msg, 0, (size_t)N_ENC * HDIM * sizeof(float), stream);
    scatter_kernel<TH><<<dim3((E_JE * 32 + 255) / 256), blk, 0, stream>>>(
        h_join, src_je, dst_je, msg, E_JE);
    combine_kernel<TH><<<dim3((N_ENC + 63) / 64), blk, 0, stream>>>(
        h_enc, msg, W1t + 4 * 2 * HDIM * HDIM, b1t + 4 * HDIM,
        W2t + 4 * HDIM * HDIM, b2t + 4 * HDIM, N_ENC);

    // final MLP
    mlp128_kernel<TH><<<dim3((N_ENC + 63) / 64), blk, 0, stream>>>(h_enc, Wf1, bf1, t1, N_ENC);
    rowdot_kernel<<<dim3((N_ENC + 255) / 256), blk, 0, stream>>>(t1, Wf2, bf2, d_out, N_ENC);
}

extern "C" void kernel_launch(void* const* d_in, const int* in_sizes, int n_in,
                              void* d_out, int out_size, void* d_ws, size_t ws_size,
                              hipStream_t stream)
{
    const float* x_col  = (const float*)d_in[0];
    const float* x_filt = (const float*)d_in[1];
    const float* x_pred = (const float*)d_in[2];
    const float* x_scan = (const float*)d_in[3];
    const float* x_join = (const float*)d_in[4];
    const float* x_enc  = (const float*)d_in[5];
    const float* W_enc  = (const float*)d_in[6];
    const float* b_enc  = (const float*)d_in[7];
    const float* W1t    = (const float*)d_in[8];
    const float* b1t    = (const float*)d_in[9];
    const float* W2t    = (const float*)d_in[10];
    const float* b2t    = (const float*)d_in[11];
    const float* Wf1    = (const float*)d_in[12];
    const float* bf1    = (const float*)d_in[13];
    const float* Wf2    = (const float*)d_in[14];
    const float* bf2    = (const float*)d_in[15];
    const int* src_cf = (const int*)d_in[16];
    const int* dst_cf = (const int*)d_in[17];
    const int* src_fp = (const int*)d_in[18];
    const int* dst_fp = (const int*)d_in[19];
    const int* src_ps = (const int*)d_in[20];
    const int* dst_ps = (const int*)d_in[21];
    const int* src_sj = (const int*)d_in[22];
    const int* dst_sj = (const int*)d_in[23];
    const int* src_je = (const int*)d_in[24];
    const int* dst_je = (const int*)d_in[25];

    const int N_FILT = in_sizes[1] / FIN;
    const int N_PRED = in_sizes[2] / FIN;
    const int N_SCAN = in_sizes[3] / FIN;
    const int N_JOIN = in_sizes[4] / FIN;
    const int N_ENC  = in_sizes[5] / FIN;
    const int E_CF = in_sizes[16];
    const int E_FP = in_sizes[18];
    const int E_PS = in_sizes[20];
    const int E_SJ = in_sizes[22];
    const int E_JE = in_sizes[24];

    // workspace regions (floats):
    //   msg: largest destination level (also reused as t1, f32 in both tiers)
    //   hreg: h_filt, later aliased by h_scan+h_join+h_enc
    //   preg: h_pred
    size_t Mf = (size_t)N_FILT * HDIM;
    { size_t c;
      c = (size_t)N_PRED * HDIM; if (c > Mf) Mf = c;
      c = (size_t)N_SCAN * HDIM; if (c > Mf) Mf = c;
      c = (size_t)N_JOIN * HDIM; if (c > Mf) Mf = c;
      c = (size_t)N_ENC  * HDIM; if (c > Mf) Mf = c; }
    size_t Ff = (size_t)N_FILT * HDIM;
    { size_t c = (size_t)(N_SCAN + N_JOIN + N_ENC) * HDIM; if (c > Ff) Ff = c; }
    size_t Pf = (size_t)N_PRED * HDIM;

    size_t tierA = 4 * (Mf + Ff + Pf);   // all-fp32 (~307 MB)
    size_t tierB = 4 * Mf + 2 * (Ff + Pf); // h in bf16 (~218 MB)

    char* base = (char*)d_ws;
    float* msg = (float*)base;

    if (d_ws && ws_size >= tierA) {
        float* hreg = (float*)(base + 4 * Mf);
        float* preg = hreg + Ff;
        run_all<float>(x_col, x_filt, x_pred, x_scan, x_join, x_enc,
                       W_enc, b_enc, W1t, b1t, W2t, b2t, Wf1, bf1, Wf2, bf2,
                       src_cf, dst_cf, src_fp, dst_fp, src_ps, dst_ps,
                       src_sj, dst_sj, src_je, dst_je,
                       N_FILT, N_PRED, N_SCAN, N_JOIN, N_ENC,
                       E_CF, E_FP, E_PS, E_SJ, E_JE,
                       msg, hreg, preg, (float*)d_out, stream);
    } else if (d_ws && ws_size >= tierB) {
        bf16t* hreg = (bf16t*)(base + 4 * Mf);
        bf16t* preg = hreg + Ff;
        run_all<bf16t>(x_col, x_filt, x_pred, x_scan, x_join, x_enc,
                       W_enc, b_enc, W1t, b1t, W2t, b2t, Wf1, bf1, Wf2, bf2,
                       src_cf, dst_cf, src_fp, dst_fp, src_ps, dst_ps,
                       src_sj, dst_sj, src_je, dst_je,
                       N_FILT, N_PRED, N_SCAN, N_JOIN, N_ENC,
                       E_CF, E_FP, E_PS, E_SJ, E_JE,
                       msg, hreg, preg, (float*)d_out, stream);
    } else {
        // workspace too small even for bf16 tier: report ws_size (MB) via absmax
        float val = 1.0e6f + (float)(ws_size >> 20);
        sentinel_kernel<<<dim3((out_size + 255) / 256), dim3(256), 0, stream>>>(
            (float*)d_out, out_size, val);
    }
}

// Round 3
// 1442.383 us; speedup vs baseline: 1.5259x; 1.5259x over previous
//
#include <hip/hip_runtime.h>
#include <hip/hip_bf16.h>

#define HDIM 128
#define FIN  32

typedef __hip_bfloat16 bf16t;

__device__ __forceinline__ float reluf(float x) { return x > 0.f ? x : 0.f; }

__device__ __forceinline__ unsigned short f2bf(float f) {
    unsigned int b = __float_as_uint(f);
    b += 0x7FFFu + ((b >> 16) & 1u);       // round-to-nearest-even
    return (unsigned short)(b >> 16);
}
__device__ __forceinline__ float bf2f(unsigned short u) {
    return __uint_as_float(((unsigned int)u) << 16);
}

__device__ __forceinline__ float4 ld4(const float* p) { return *(const float4*)p; }
__device__ __forceinline__ float4 ld4(const bf16t* p) {
    ushort4 u = *(const ushort4*)p;
    return make_float4(bf2f(u.x), bf2f(u.y), bf2f(u.z), bf2f(u.w));
}
__device__ __forceinline__ void st4(float* p, float4 v) { *(float4*)p = v; }
__device__ __forceinline__ void st4(bf16t* p, float4 v) {
    ushort4 u;
    u.x = f2bf(v.x); u.y = f2bf(v.y); u.z = f2bf(v.z); u.w = f2bf(v.w);
    *(ushort4*)p = u;
}

// ---------------------------------------------------------------------------
// Encoder: h = relu(x @ W + b); x:[N,32], W:[32,128].
// ---------------------------------------------------------------------------
template<typename T>
__global__ __launch_bounds__(256) void enc_kernel(
    const float* __restrict__ x, const float* __restrict__ W,
    const float* __restrict__ b, T* __restrict__ h, int N)
{
    __shared__ float w_s[FIN * HDIM];
    __shared__ float x_s[64 * 36];
    const int tid  = threadIdx.x;
    const int row0 = blockIdx.x * 64;

    #pragma unroll
    for (int i = 0; i < 4; ++i) {
        int f = tid + i * 256;
        int r = f >> 5, c4 = f & 31;
        *(float4*)&w_s[r * HDIM + c4 * 4] =
            *(const float4*)&W[(size_t)r * HDIM + c4 * 4];
    }
    #pragma unroll
    for (int i = 0; i < 2; ++i) {
        int f = tid + i * 256;
        int r = f >> 3, c4 = f & 7;
        float4 v = make_float4(0.f, 0.f, 0.f, 0.f);
        if (row0 + r < N)
            v = *(const float4*)&x[(size_t)(row0 + r) * FIN + c4 * 4];
        *(float4*)&x_s[r * 36 + c4 * 4] = v;
    }
    __syncthreads();

    const int tr = tid >> 4, tc = tid & 15, trow = tr * 4;
    float acc[4][8] = {};
    #pragma unroll
    for (int k = 0; k < FIN; ++k) {
        float av[4];
        #pragma unroll
        for (int r = 0; r < 4; ++r) av[r] = x_s[(trow + r) * 36 + k];
        float4 w0 = *(float4*)&w_s[k * HDIM + tc * 8];
        float4 w1 = *(float4*)&w_s[k * HDIM + tc * 8 + 4];
        float wv[8] = {w0.x, w0.y, w0.z, w0.w, w1.x, w1.y, w1.z, w1.w};
        #pragma unroll
        for (int r = 0; r < 4; ++r)
            #pragma unroll
            for (int c = 0; c < 8; ++c)
                acc[r][c] += av[r] * wv[c];
    }

    float4 b0 = *(const float4*)&b[tc * 8];
    float4 b1 = *(const float4*)&b[tc * 8 + 4];
    float bv[8] = {b0.x, b0.y, b0.z, b0.w, b1.x, b1.y, b1.z, b1.w};
    #pragma unroll
    for (int r = 0; r < 4; ++r) {
        int row = row0 + trow + r;
        if (row < N) {
            float4 o0 = make_float4(reluf(acc[r][0] + bv[0]), reluf(acc[r][1] + bv[1]),
                                    reluf(acc[r][2] + bv[2]), reluf(acc[r][3] + bv[3]));
            float4 o1 = make_float4(reluf(acc[r][4] + bv[4]), reluf(acc[r][5] + bv[5]),
                                    reluf(acc[r][6] + bv[6]), reluf(acc[r][7] + bv[7]));
            st4(&h[(size_t)row * HDIM + tc * 8],     o0);
            st4(&h[(size_t)row * HDIM + tc * 8 + 4], o1);
        }
    }
}

// ======================= CSR construction ===================================
__global__ __launch_bounds__(256) void hist_kernel(
    const int* __restrict__ dst, int* __restrict__ deg, int E)
{
    int i = blockIdx.x * 256 + threadIdx.x;
    if (i < E) atomicAdd(&deg[dst[i]], 1);
}

// per-1024-chunk exclusive scan; bsum[chunk] = chunk total
__global__ __launch_bounds__(256) void scan_blocks_kernel(
    const int* __restrict__ deg, int* __restrict__ start,
    int* __restrict__ bsum, int N)
{
    __shared__ int s[256];
    const int t = threadIdx.x;
    const int base = blockIdx.x * 1024;
    int v[4], tsum = 0;
    #pragma unroll
    for (int i = 0; i < 4; ++i) {
        int idx = base + t * 4 + i;
        v[i] = (idx < N) ? deg[idx] : 0;
        tsum += v[i];
    }
    s[t] = tsum; __syncthreads();
    for (int off = 1; off < 256; off <<= 1) {
        int x = (t >= off) ? s[t - off] : 0;
        __syncthreads();
        s[t] += x;
        __syncthreads();
    }
    if (t == 255) bsum[blockIdx.x] = s[255];
    int run = s[t] - tsum;
    #pragma unroll
    for (int i = 0; i < 4; ++i) {
        int idx = base + t * 4 + i;
        if (idx < N) start[idx] = run;
        run += v[i];
    }
}

// single-block exclusive scan of bsum[B], B <= 1024
__global__ __launch_bounds__(256) void scan_top_kernel(int* __restrict__ bsum, int B)
{
    __shared__ int s[256];
    const int t = threadIdx.x;
    int v[4], tsum = 0;
    #pragma unroll
    for (int i = 0; i < 4; ++i) {
        int idx = t * 4 + i;
        v[i] = (idx < B) ? bsum[idx] : 0;
        tsum += v[i];
    }
    s[t] = tsum; __syncthreads();
    for (int off = 1; off < 256; off <<= 1) {
        int x = (t >= off) ? s[t - off] : 0;
        __syncthreads();
        s[t] += x;
        __syncthreads();
    }
    int run = s[t] - tsum;
    #pragma unroll
    for (int i = 0; i < 4; ++i) {
        int idx = t * 4 + i;
        if (idx < B) bsum[idx] = run;
        run += v[i];
    }
}

__global__ __launch_bounds__(256) void scan_add_kernel(
    int* __restrict__ start, int* __restrict__ cursor,
    const int* __restrict__ bsum, int N)
{
    int i = blockIdx.x * 256 + threadIdx.x;
    if (i < N) {
        int v = start[i] + bsum[i >> 10];
        start[i]  = v;
        cursor[i] = v;
    }
}

__global__ __launch_bounds__(256) void fill_kernel(
    const int* __restrict__ src, const int* __restrict__ dst,
    int* __restrict__ cursor, int* __restrict__ eidx, int E)
{
    int i = blockIdx.x * 256 + threadIdx.x;
    if (i < E) {
        int d = dst[i];
        int p = atomicAdd(&cursor[d], 1);
        eidx[p] = src[i];
    }
}

// ======================= gather-based segment sums ==========================
// msg[r] = sum_{j in CSR[r]} h[eidx[j]]   (32 lanes per row, 8 rows/block)
template<typename T>
__global__ __launch_bounds__(256) void gather_kernel(
    const T* __restrict__ h, const int* __restrict__ eidx,
    const int* __restrict__ start, const int* __restrict__ deg,
    T* __restrict__ msg, int N)
{
    int r = blockIdx.x * 8 + (threadIdx.x >> 5);
    if (r >= N) return;
    int lane = threadIdx.x & 31;
    int s0 = start[r], cnt = deg[r];
    float4 acc = make_float4(0.f, 0.f, 0.f, 0.f);
    for (int j = s0; j < s0 + cnt; ++j) {
        int s = eidx[j];
        float4 v = ld4(&h[(size_t)s * HDIM + lane * 4]);
        acc.x += v.x; acc.y += v.y; acc.z += v.z; acc.w += v.w;
    }
    st4(&msg[(size_t)r * HDIM + lane * 4], acc);
}

// Level-0 fused: msg[r] = sum_{j} relu(x_col[eidx[j]] @ W0 + b0)
// one wave per dst row; W0 staged in LDS.
template<typename T>
__global__ __launch_bounds__(256) void enc_gather_kernel(
    const float* __restrict__ x, const int* __restrict__ eidx,
    const int* __restrict__ start, const int* __restrict__ deg,
    const float* __restrict__ W, const float* __restrict__ b,
    T* __restrict__ msg, int N)
{
    __shared__ float w_s[FIN * HDIM];   // 16 KB
    for (int i = threadIdx.x; i < FIN * HDIM / 4; i += 256)
        ((float4*)w_s)[i] = ((const float4*)W)[i];
    __syncthreads();

    const int wid  = blockIdx.x * 4 + (threadIdx.x >> 6);
    const int lane = threadIdx.x & 63;
    if (wid >= N) return;

    const float b0 = b[lane], b1 = b[64 + lane];
    int s0 = start[wid], cnt = deg[wid];
    float m0 = 0.f, m1 = 0.f;
    for (int j = s0; j < s0 + cnt; ++j) {
        int s = eidx[j];
        float xv = x[(size_t)s * FIN + (lane & 31)];
        float a0 = 0.f, a1 = 0.f;
        #pragma unroll
        for (int k = 0; k < FIN; ++k) {
            float xk = __shfl(xv, k, 64);
            a0 += xk * w_s[k * HDIM + lane];
            a1 += xk * w_s[k * HDIM + 64 + lane];
        }
        m0 += reluf(a0 + b0);
        m1 += reluf(a1 + b1);
    }
    msg[(size_t)wid * HDIM + lane]      = (T)__uint_as_float(((unsigned)f2bf(m0)) << 16);
    msg[(size_t)wid * HDIM + 64 + lane] = (T)__uint_as_float(((unsigned)f2bf(m1)) << 16);
}

// specialization-friendly scalar store helpers
__device__ __forceinline__ void st1(float* p, float v) { *p = v; }
__device__ __forceinline__ void st1(bf16t* p, float v) {
    *(unsigned short*)p = f2bf(v);
}

// cleaner enc_gather store (overrides the hacky cast above)
template<typename T>
__global__ __launch_bounds__(256) void enc_gather2_kernel(
    const float* __restrict__ x, const int* __restrict__ eidx,
    const int* __restrict__ start, const int* __restrict__ deg,
    const float* __restrict__ W, const float* __restrict__ b,
    T* __restrict__ msg, int N)
{
    __shared__ float w_s[FIN * HDIM];
    for (int i = threadIdx.x; i < FIN * HDIM / 4; i += 256)
        ((float4*)w_s)[i] = ((const float4*)W)[i];
    __syncthreads();

    const int wid  = blockIdx.x * 4 + (threadIdx.x >> 6);
    const int lane = threadIdx.x & 63;
    if (wid >= N) return;

    const float b0 = b[lane], b1 = b[64 + lane];
    int s0 = start[wid], cnt = deg[wid];
    float m0 = 0.f, m1 = 0.f;
    for (int j = s0; j < s0 + cnt; ++j) {
        int s = eidx[j];
        float xv = x[(size_t)s * FIN + (lane & 31)];
        float a0 = 0.f, a1 = 0.f;
        #pragma unroll
        for (int k = 0; k < FIN; ++k) {
            float xk = __shfl(xv, k, 64);
            a0 += xk * w_s[k * HDIM + lane];
            a1 += xk * w_s[k * HDIM + 64 + lane];
        }
        m0 += reluf(a0 + b0);
        m1 += reluf(a1 + b1);
    }
    st1(&msg[(size_t)wid * HDIM + lane],      m0);
    st1(&msg[(size_t)wid * HDIM + 64 + lane], m1);
}

// ---------------------------------------------------------------------------
// Combine (fused 2-layer MLP, in-place on hd):
//   z1 = relu([hd | msg] @ W1 + b1); hd = relu(z1 @ W2 + b2)
// ---------------------------------------------------------------------------
template<typename TH>
__global__ __launch_bounds__(256) void combine_kernel(
    TH* __restrict__ hd, const TH* __restrict__ msg,
    const float* __restrict__ W1, const float* __restrict__ b1,
    const float* __restrict__ W2, const float* __restrict__ b2, int N)
{
    __shared__ float smem[12544];        // 50,176 B
    float* z_s = smem;                   // 64x128, stride 132
    float* a_s = smem + 4096;            // 64x64,  stride 68
    float* w_s = smem + 8448;            // 32x128

    const int tid  = threadIdx.x;
    const int row0 = blockIdx.x * 64;
    const int tr = tid >> 4, tc = tid & 15, trow = tr * 4;

    float acc[4][8] = {};

    for (int half = 0; half < 4; ++half) {
        __syncthreads();
        const int koff = (half & 1) * 64;
        #pragma unroll
        for (int i = 0; i < 4; ++i) {
            int f = tid + i * 256;
            int r = f >> 4, c4 = f & 15;
            float4 v = make_float4(0.f, 0.f, 0.f, 0.f);
            if (row0 + r < N) {
                if (half < 2) v = ld4(&hd [(size_t)(row0 + r) * HDIM + koff + c4 * 4]);
                else          v = ld4(&msg[(size_t)(row0 + r) * HDIM + koff + c4 * 4]);
            }
            *(float4*)&a_s[r * 68 + c4 * 4] = v;
        }
        #pragma unroll
        for (int sub = 0; sub < 2; ++sub) {
            if (sub) __syncthreads();
            #pragma unroll
            for (int i = 0; i < 4; ++i) {
                int f = tid + i * 256;
                int r = f >> 5, c4 = f & 31;
                *(float4*)&w_s[r * HDIM + c4 * 4] =
                    *(const float4*)&W1[(size_t)(half * 64 + sub * 32 + r) * HDIM + c4 * 4];
            }
            __syncthreads();
            #pragma unroll 2
            for (int k = 0; k < 32; ++k) {
                float av[4];
                #pragma unroll
                for (int r = 0; r < 4; ++r)
                    av[r] = a_s[(trow + r) * 68 + sub * 32 + k];
                float4 w0 = *(float4*)&w_s[k * HDIM + tc * 8];
                float4 w1 = *(float4*)&w_s[k * HDIM + tc * 8 + 4];
                float wv[8] = {w0.x, w0.y, w0.z, w0.w, w1.x, w1.y, w1.z, w1.w};
                #pragma unroll
                for (int r = 0; r < 4; ++r)
                    #pragma unroll
                    for (int c = 0; c < 8; ++c)
                        acc[r][c] += av[r] * wv[c];
            }
        }
    }

    __syncthreads();

    {
        float4 ba = *(const float4*)&b1[tc * 8];
        float4 bb = *(const float4*)&b1[tc * 8 + 4];
        float bv[8] = {ba.x, ba.y, ba.z, ba.w, bb.x, bb.y, bb.z, bb.w};
        #pragma unroll
        for (int r = 0; r < 4; ++r) {
            float4 z0 = make_float4(reluf(acc[r][0] + bv[0]), reluf(acc[r][1] + bv[1]),
                                    reluf(acc[r][2] + bv[2]), reluf(acc[r][3] + bv[3]));
            float4 z1 = make_float4(reluf(acc[r][4] + bv[4]), reluf(acc[r][5] + bv[5]),
                                    reluf(acc[r][6] + bv[6]), reluf(acc[r][7] + bv[7]));
            *(float4*)&z_s[(trow + r) * 132 + tc * 8]     = z0;
            *(float4*)&z_s[(trow + r) * 132 + tc * 8 + 4] = z1;
            #pragma unroll
            for (int c = 0; c < 8; ++c) acc[r][c] = 0.f;
        }
    }

    for (int kc = 0; kc < 4; ++kc) {
        if (kc) __syncthreads();
        #pragma unroll
        for (int i = 0; i < 4; ++i) {
            int f = tid + i * 256;
            int r = f >> 5, c4 = f & 31;
            *(float4*)&w_s[r * HDIM + c4 * 4] =
                *(const float4*)&W2[(size_t)(kc * 32 + r) * HDIM + c4 * 4];
        }
        __syncthreads();
        #pragma unroll 2
        for (int k = 0; k < 32; ++k) {
            float av[4];
            #pragma unroll
            for (int r = 0; r < 4; ++r)
                av[r] = z_s[(trow + r) * 132 + kc * 32 + k];
            float4 w0 = *(float4*)&w_s[k * HDIM + tc * 8];
            float4 w1 = *(float4*)&w_s[k * HDIM + tc * 8 + 4];
            float wv[8] = {w0.x, w0.y, w0.z, w0.w, w1.x, w1.y, w1.z, w1.w};
            #pragma unroll
            for (int r = 0; r < 4; ++r)
                #pragma unroll
                for (int c = 0; c < 8; ++c)
                    acc[r][c] += av[r] * wv[c];
        }
    }

    float4 ba = *(const float4*)&b2[tc * 8];
    float4 bb = *(const float4*)&b2[tc * 8 + 4];
    float bv[8] = {ba.x, ba.y, ba.z, ba.w, bb.x, bb.y, bb.z, bb.w};
    #pragma unroll
    for (int r = 0; r < 4; ++r) {
        int row = row0 + trow + r;
        if (row < N) {
            float4 o0 = make_float4(reluf(acc[r][0] + bv[0]), reluf(acc[r][1] + bv[1]),
                                    reluf(acc[r][2] + bv[2]), reluf(acc[r][3] + bv[3]));
            float4 o1 = make_float4(reluf(acc[r][4] + bv[4]), reluf(acc[r][5] + bv[5]),
                                    reluf(acc[r][6] + bv[6]), reluf(acc[r][7] + bv[7]));
            st4(&hd[(size_t)row * HDIM + tc * 8],     o0);
            st4(&hd[(size_t)row * HDIM + tc * 8 + 4], o1);
        }
    }
}

// ---------------------------------------------------------------------------
// out = relu(in @ W + b), in:[N,128], W:[128,128]
// ---------------------------------------------------------------------------
template<typename TH>
__global__ __launch_bounds__(256) void mlp128_kernel(
    const TH* __restrict__ in, const float* __restrict__ W,
    const float* __restrict__ b, float* __restrict__ out, int N)
{
    __shared__ float smem[12544];
    float* a_s = smem;                   // 64x128 stride 132
    float* w_s = smem + 8448;            // 32x128

    const int tid  = threadIdx.x;
    const int row0 = blockIdx.x * 64;
    const int tr = tid >> 4, tc = tid & 15, trow = tr * 4;

    #pragma unroll
    for (int i = 0; i < 8; ++i) {
        int f = tid + i * 256;
        int r = f >> 5, c4 = f & 31;
        float4 v = make_float4(0.f, 0.f, 0.f, 0.f);
        if (row0 + r < N)
            v = ld4(&in[(size_t)(row0 + r) * HDIM + c4 * 4]);
        *(float4*)&a_s[r * 132 + c4 * 4] = v;
    }

    float acc[4][8] = {};
    for (int kc = 0; kc < 4; ++kc) {
        if (kc) __syncthreads();
        #pragma unroll
        for (int i = 0; i < 4; ++i) {
            int f = tid + i * 256;
            int r = f >> 5, c4 = f & 31;
            *(float4*)&w_s[r * HDIM + c4 * 4] =
                *(const float4*)&W[(size_t)(kc * 32 + r) * HDIM + c4 * 4];
        }
        __syncthreads();
        #pragma unroll 2
        for (int k = 0; k < 32; ++k) {
            float av[4];
            #pragma unroll
            for (int r = 0; r < 4; ++r)
                av[r] = a_s[(trow + r) * 132 + kc * 32 + k];
            float4 w0 = *(float4*)&w_s[k * HDIM + tc * 8];
            float4 w1 = *(float4*)&w_s[k * HDIM + tc * 8 + 4];
            float wv[8] = {w0.x, w0.y, w0.z, w0.w, w1.x, w1.y, w1.z, w1.w};
            #pragma unroll
            for (int r = 0; r < 4; ++r)
                #pragma unroll
                for (int c = 0; c < 8; ++c)
                    acc[r][c] += av[r] * wv[c];
        }
    }

    float4 ba = *(const float4*)&b[tc * 8];
    float4 bb = *(const float4*)&b[tc * 8 + 4];
    float bv[8] = {ba.x, ba.y, ba.z, ba.w, bb.x, bb.y, bb.z, bb.w};
    #pragma unroll
    for (int r = 0; r < 4; ++r) {
        int row = row0 + trow + r;
        if (row < N) {
            float4 o0 = make_float4(reluf(acc[r][0] + bv[0]), reluf(acc[r][1] + bv[1]),
                                    reluf(acc[r][2] + bv[2]), reluf(acc[r][3] + bv[3]));
            float4 o1 = make_float4(reluf(acc[r][4] + bv[4]), reluf(acc[r][5] + bv[5]),
                                    reluf(acc[r][6] + bv[6]), reluf(acc[r][7] + bv[7]));
            *(float4*)&out[(size_t)row * HDIM + tc * 8]     = o0;
            *(float4*)&out[(size_t)row * HDIM + tc * 8 + 4] = o1;
        }
    }
}

__global__ __launch_bounds__(256) void rowdot_kernel(
    const float* __restrict__ t1, const float* __restrict__ w,
    const float* __restrict__ b, float* __restrict__ out, int N)
{
    __shared__ float w_s[HDIM];
    if (threadIdx.x < 32)
        *(float4*)&w_s[threadIdx.x * 4] = *(const float4*)&w[threadIdx.x * 4];
    __syncthreads();
    int row = blockIdx.x * 256 + threadIdx.x;
    if (row >= N) return;
    float acc = 0.f;
    #pragma unroll
    for (int k4 = 0; k4 < 32; ++k4) {
        float4 v = *(const float4*)&t1[(size_t)row * HDIM + k4 * 4];
        acc += v.x * w_s[k4 * 4] + v.y * w_s[k4 * 4 + 1]
             + v.z * w_s[k4 * 4 + 2] + v.w * w_s[k4 * 4 + 3];
    }
    out[row] = acc + b[0];
}

__global__ __launch_bounds__(256) void sentinel_kernel(float* out, int n, float val)
{
    int i = blockIdx.x * 256 + threadIdx.x;
    if (i < n) out[i] = (i == 0) ? val : 0.f;
}

// ---------------------------------------------------------------------------
static void build_csr(const int* src, const int* dst, int E, int N,
                      int* deg, int* start, int* cursor, int* eidx, int* bsum,
                      hipStream_t stream)
{
    const dim3 blk(256);
    hipMemsetAsync(deg, 0, (size_t)N * sizeof(int), stream);
    hist_kernel<<<dim3((E + 255) / 256), blk, 0, stream>>>(dst, deg, E);
    int B = (N + 1023) / 1024;
    scan_blocks_kernel<<<dim3(B), blk, 0, stream>>>(deg, start, bsum, N);
    scan_top_kernel<<<dim3(1), blk, 0, stream>>>(bsum, B);
    scan_add_kernel<<<dim3((N + 255) / 256), blk, 0, stream>>>(start, cursor, bsum, N);
    fill_kernel<<<dim3((E + 255) / 256), blk, 0, stream>>>(src, dst, cursor, eidx, E);
}

extern "C" void kernel_launch(void* const* d_in, const int* in_sizes, int n_in,
                              void* d_out, int out_size, void* d_ws, size_t ws_size,
                              hipStream_t stream)
{
    const float* x_col  = (const float*)d_in[0];
    const float* x_filt = (const float*)d_in[1];
    const float* x_pred = (const float*)d_in[2];
    const float* x_scan = (const float*)d_in[3];
    const float* x_join = (const float*)d_in[4];
    const float* x_enc  = (const float*)d_in[5];
    const float* W_enc  = (const float*)d_in[6];
    const float* b_enc  = (const float*)d_in[7];
    const float* W1t    = (const float*)d_in[8];
    const float* b1t    = (const float*)d_in[9];
    const float* W2t    = (const float*)d_in[10];
    const float* b2t    = (const float*)d_in[11];
    const float* Wf1    = (const float*)d_in[12];
    const float* bf1    = (const float*)d_in[13];
    const float* Wf2    = (const float*)d_in[14];
    const float* bf2    = (const float*)d_in[15];
    const int* src_cf = (const int*)d_in[16];
    const int* dst_cf = (const int*)d_in[17];
    const int* src_fp = (const int*)d_in[18];
    const int* dst_fp = (const int*)d_in[19];
    const int* src_ps = (const int*)d_in[20];
    const int* dst_ps = (const int*)d_in[21];
    const int* src_sj = (const int*)d_in[22];
    const int* dst_sj = (const int*)d_in[23];
    const int* src_je = (const int*)d_in[24];
    const int* dst_je = (const int*)d_in[25];

    const int N_FILT = in_sizes[1] / FIN;
    const int N_PRED = in_sizes[2] / FIN;
    const int N_SCAN = in_sizes[3] / FIN;
    const int N_JOIN = in_sizes[4] / FIN;
    const int N_ENC  = in_sizes[5] / FIN;
    const int E_CF = in_sizes[16];
    const int E_FP = in_sizes[18];
    const int E_PS = in_sizes[20];
    const int E_SJ = in_sizes[22];
    const int E_JE = in_sizes[24];

    // ---- workspace layout (all h/msg in bf16; CSR scratch in int) ----
    size_t Mf = 0;   // max dst-level row count * HDIM  (msg elems)
    {
        size_t c;
        c = (size_t)N_FILT * HDIM; if (c > Mf) Mf = c;
        c = (size_t)N_PRED * HDIM; if (c > Mf) Mf = c;
        c = (size_t)N_SCAN * HDIM; if (c > Mf) Mf = c;
        c = (size_t)N_JOIN * HDIM; if (c > Mf) Mf = c;
        c = (size_t)N_ENC  * HDIM; if (c > Mf) Mf = c;
    }
    size_t Ff = (size_t)N_FILT * HDIM;
    { size_t c = (size_t)(N_SCAN + N_JOIN + N_ENC) * HDIM; if (c > Ff) Ff = c; }
    size_t Pf = (size_t)N_PRED * HDIM;

    int maxN = N_FILT;
    if (N_PRED > maxN) maxN = N_PRED;
    if (N_SCAN > maxN) maxN = N_SCAN;
    if (N_JOIN > maxN) maxN = N_JOIN;
    if (N_ENC  > maxN) maxN = N_ENC;
    int maxE = E_CF;
    if (E_FP > maxE) maxE = E_FP;
    if (E_PS > maxE) maxE = E_PS;
    if (E_SJ > maxE) maxE = E_SJ;
    if (E_JE > maxE) maxE = E_JE;

    size_t msgB = Mf * 2;                          // bf16 msg (also t1 fp32 later)
    size_t t1B  = (size_t)N_ENC * HDIM * 4;
    if (t1B > msgB) msgB = t1B;
    msgB = (msgB + 255) & ~(size_t)255;
    size_t hregB = ((Ff * 2) + 255) & ~(size_t)255;
    size_t pregB = ((Pf * 2) + 255) & ~(size_t)255;
    size_t intB  = (size_t)maxN * 4;
    intB = (intB + 255) & ~(size_t)255;
    size_t eidxB = ((size_t)maxE * 4 + 255) & ~(size_t)255;
    size_t need = msgB + hregB + pregB + 3 * intB + eidxB + 4096;

    if (!d_ws || ws_size < need) {
        float val = 1.0e6f + (float)(ws_size >> 20);
        sentinel_kernel<<<dim3((out_size + 255) / 256), dim3(256), 0, stream>>>(
            (float*)d_out, out_size, val);
        return;
    }

    char* base = (char*)d_ws;
    bf16t* msg  = (bf16t*)base;                       base += msgB;
    bf16t* hreg = (bf16t*)base;                       base += hregB;
    bf16t* preg = (bf16t*)base;                       base += pregB;
    int* deg    = (int*)base;                         base += intB;
    int* start  = (int*)base;                         base += intB;
    int* cursor = (int*)base;                         base += intB;
    int* eidx   = (int*)base;                         base += eidxB;
    int* bsum   = (int*)base;

    bf16t* h_filt = hreg;
    bf16t* h_pred = preg;
    bf16t* h_scan = hreg;                              // alias (h_filt dead by then)
    bf16t* h_join = hreg + (size_t)N_SCAN * HDIM;
    bf16t* h_enc  = hreg + (size_t)(N_SCAN + N_JOIN) * HDIM;
    float* t1     = (float*)msg;                       // alias (msg dead by then)

    const dim3 blk(256);

    // ---- level 0: column -> filter (encoder fused into gather) ----
    enc_kernel<bf16t><<<dim3((N_FILT + 63) / 64), blk, 0, stream>>>(
        x_filt, W_enc + 1 * FIN * HDIM, b_enc + 1 * HDIM, h_filt, N_FILT);
    build_csr(src_cf, dst_cf, E_CF, N_FILT, deg, start, cursor, eidx, bsum, stream);
    enc_gather2_kernel<bf16t><<<dim3((N_FILT + 3) / 4), blk, 0, stream>>>(
        x_col, eidx, start, deg, W_enc, b_enc, msg, N_FILT);
    combine_kernel<bf16t><<<dim3((N_FILT + 63) / 64), blk, 0, stream>>>(
        h_filt, msg, W1t, b1t, W2t, b2t, N_FILT);

    // ---- level 1: filter -> pred ----
    enc_kernel<bf16t><<<dim3((N_PRED + 63) / 64), blk, 0, stream>>>(
        x_pred, W_enc + 2 * FIN * HDIM, b_enc + 2 * HDIM, h_pred, N_PRED);
    build_csr(src_fp, dst_fp, E_FP, N_PRED, deg, start, cursor, eidx, bsum, stream);
    gather_kernel<bf16t><<<dim3((N_PRED + 7) / 8), blk, 0, stream>>>(
        h_filt, eidx, start, deg, msg, N_PRED);
    combine_kernel<bf16t><<<dim3((N_PRED + 63) / 64), blk, 0, stream>>>(
        h_pred, msg, W1t + 1 * 2 * HDIM * HDIM, b1t + 1 * HDIM,
        W2t + 1 * HDIM * HDIM, b2t + 1 * HDIM, N_PRED);

    // ---- level 2: pred -> scan (h_scan reuses dead h_filt region) ----
    enc_kernel<bf16t><<<dim3((N_SCAN + 63) / 64), blk, 0, stream>>>(
        x_scan, W_enc + 3 * FIN * HDIM, b_enc + 3 * HDIM, h_scan, N_SCAN);
    build_csr(src_ps, dst_ps, E_PS, N_SCAN, deg, start, cursor, eidx, bsum, stream);
    gather_kernel<bf16t><<<dim3((N_SCAN + 7) / 8), blk, 0, stream>>>(
        h_pred, eidx, start, deg, msg, N_SCAN);
    combine_kernel<bf16t><<<dim3((N_SCAN + 63) / 64), blk, 0, stream>>>(
        h_scan, msg, W1t + 2 * 2 * HDIM * HDIM, b1t + 2 * HDIM,
        W2t + 2 * HDIM * HDIM, b2t + 2 * HDIM, N_SCAN);

    // ---- level 3: scan -> join ----
    enc_kernel<bf16t><<<dim3((N_JOIN + 63) / 64), blk, 0, stream>>>(
        x_join, W_enc + 4 * FIN * HDIM, b_enc + 4 * HDIM, h_join, N_JOIN);
    build_csr(src_sj, dst_sj, E_SJ, N_JOIN, deg, start, cursor, eidx, bsum, stream);
    gather_kernel<bf16t><<<dim3((N_JOIN + 7) / 8), blk, 0, stream>>>(
        h_scan, eidx, start, deg, msg, N_JOIN);
    combine_kernel<bf16t><<<dim3((N_JOIN + 63) / 64), blk, 0, stream>>>(
        h_join, msg, W1t + 3 * 2 * HDIM * HDIM, b1t + 3 * HDIM,
        W2t + 3 * HDIM * HDIM, b2t + 3 * HDIM, N_JOIN);

    // ---- level 4: join -> encode ----
    enc_kernel<bf16t><<<dim3((N_ENC + 63) / 64), blk, 0, stream>>>(
        x_enc, W_enc + 5 * FIN * HDIM, b_enc + 5 * HDIM, h_enc, N_ENC);
    build_csr(src_je, dst_je, E_JE, N_ENC, deg, start, cursor, eidx, bsum, stream);
    gather_kernel<bf16t><<<dim3((N_ENC + 7) / 8), blk, 0, stream>>>(
        h_join, eidx, start, deg, msg, N_ENC);
    combine_kernel<bf16t><<<dim3((N_ENC + 63) / 64), blk, 0, stream>>>(
        h_enc, msg, W1t + 4 * 2 * HDIM * HDIM, b1t + 4 * HDIM,
        W2t + 4 * HDIM * HDIM, b2t + 4 * HDIM, N_ENC);

    // ---- final MLP ----
    mlp128_kernel<bf16t><<<dim3((N_ENC + 63) / 64), blk, 0, stream>>>(h_enc, Wf1, bf1, t1, N_ENC);
    rowdot_kernel<<<dim3((N_ENC + 255) / 256), blk, 0, stream>>>(t1, Wf2, bf2, (float*)d_out, N_ENC);
}

// Round 4
// 807.468 us; speedup vs baseline: 2.7256x; 1.7863x over previous
//
#include <hip/hip_runtime.h>
#include <hip/hip_bf16.h>

#define HDIM 128
#define FIN  32

typedef __hip_bfloat16 bf16t;
using bf16x8 = __attribute__((ext_vector_type(8))) short;
using f32x4  = __attribute__((ext_vector_type(4))) float;

__device__ __forceinline__ float reluf(float x) { return x > 0.f ? x : 0.f; }

__device__ __forceinline__ unsigned short f2bf(float f) {
    unsigned int b = __float_as_uint(f);
    b += 0x7FFFu + ((b >> 16) & 1u);       // round-to-nearest-even
    return (unsigned short)(b >> 16);
}
__device__ __forceinline__ float bf2f(unsigned short u) {
    return __uint_as_float(((unsigned int)u) << 16);
}

__device__ __forceinline__ float4 ld4(const bf16t* p) {
    ushort4 u = *(const ushort4*)p;
    return make_float4(bf2f(u.x), bf2f(u.y), bf2f(u.z), bf2f(u.w));
}
__device__ __forceinline__ void st4(bf16t* p, float4 v) {
    ushort4 u;
    u.x = f2bf(v.x); u.y = f2bf(v.y); u.z = f2bf(v.z); u.w = f2bf(v.w);
    *(ushort4*)p = u;
}

// ---------------------------------------------------------------------------
// Encoder: h = relu(x @ W + b); x:[N,32] fp32, W:[32,128] fp32, h bf16.
// ---------------------------------------------------------------------------
__global__ __launch_bounds__(256) void enc_kernel(
    const float* __restrict__ x, const float* __restrict__ W,
    const float* __restrict__ b, bf16t* __restrict__ h, int N)
{
    __shared__ float w_s[FIN * HDIM];
    __shared__ float x_s[64 * 36];
    const int tid  = threadIdx.x;
    const int row0 = blockIdx.x * 64;

    #pragma unroll
    for (int i = 0; i < 4; ++i) {
        int f = tid + i * 256;
        int r = f >> 5, c4 = f & 31;
        *(float4*)&w_s[r * HDIM + c4 * 4] =
            *(const float4*)&W[(size_t)r * HDIM + c4 * 4];
    }
    #pragma unroll
    for (int i = 0; i < 2; ++i) {
        int f = tid + i * 256;
        int r = f >> 3, c4 = f & 7;
        float4 v = make_float4(0.f, 0.f, 0.f, 0.f);
        if (row0 + r < N)
            v = *(const float4*)&x[(size_t)(row0 + r) * FIN + c4 * 4];
        *(float4*)&x_s[r * 36 + c4 * 4] = v;
    }
    __syncthreads();

    const int tr = tid >> 4, tc = tid & 15, trow = tr * 4;
    float acc[4][8] = {};
    #pragma unroll
    for (int k = 0; k < FIN; ++k) {
        float av[4];
        #pragma unroll
        for (int r = 0; r < 4; ++r) av[r] = x_s[(trow + r) * 36 + k];
        float4 w0 = *(float4*)&w_s[k * HDIM + tc * 8];
        float4 w1 = *(float4*)&w_s[k * HDIM + tc * 8 + 4];
        float wv[8] = {w0.x, w0.y, w0.z, w0.w, w1.x, w1.y, w1.z, w1.w};
        #pragma unroll
        for (int r = 0; r < 4; ++r)
            #pragma unroll
            for (int c = 0; c < 8; ++c)
                acc[r][c] += av[r] * wv[c];
    }

    float4 b0 = *(const float4*)&b[tc * 8];
    float4 b1 = *(const float4*)&b[tc * 8 + 4];
    float bv[8] = {b0.x, b0.y, b0.z, b0.w, b1.x, b1.y, b1.z, b1.w};
    #pragma unroll
    for (int r = 0; r < 4; ++r) {
        int row = row0 + trow + r;
        if (row < N) {
            float4 o0 = make_float4(reluf(acc[r][0] + bv[0]), reluf(acc[r][1] + bv[1]),
                                    reluf(acc[r][2] + bv[2]), reluf(acc[r][3] + bv[3]));
            float4 o1 = make_float4(reluf(acc[r][4] + bv[4]), reluf(acc[r][5] + bv[5]),
                                    reluf(acc[r][6] + bv[6]), reluf(acc[r][7] + bv[7]));
            st4(&h[(size_t)row * HDIM + tc * 8],     o0);
            st4(&h[(size_t)row * HDIM + tc * 8 + 4], o1);
        }
    }
}

// ======================= CSR construction ===================================
__global__ __launch_bounds__(256) void hist_kernel(
    const int* __restrict__ dst, int* __restrict__ deg, int E)
{
    int i = blockIdx.x * 256 + threadIdx.x;
    if (i < E) atomicAdd(&deg[dst[i]], 1);
}

__global__ __launch_bounds__(256) void scan_blocks_kernel(
    const int* __restrict__ deg, int* __restrict__ start,
    int* __restrict__ bsum, int N)
{
    __shared__ int s[256];
    const int t = threadIdx.x;
    const int base = blockIdx.x * 1024;
    int v[4], tsum = 0;
    #pragma unroll
    for (int i = 0; i < 4; ++i) {
        int idx = base + t * 4 + i;
        v[i] = (idx < N) ? deg[idx] : 0;
        tsum += v[i];
    }
    s[t] = tsum; __syncthreads();
    for (int off = 1; off < 256; off <<= 1) {
        int x = (t >= off) ? s[t - off] : 0;
        __syncthreads();
        s[t] += x;
        __syncthreads();
    }
    if (t == 255) bsum[blockIdx.x] = s[255];
    int run = s[t] - tsum;
    #pragma unroll
    for (int i = 0; i < 4; ++i) {
        int idx = base + t * 4 + i;
        if (idx < N) start[idx] = run;
        run += v[i];
    }
}

__global__ __launch_bounds__(256) void scan_top_kernel(int* __restrict__ bsum, int B)
{
    __shared__ int s[256];
    const int t = threadIdx.x;
    int v[4], tsum = 0;
    #pragma unroll
    for (int i = 0; i < 4; ++i) {
        int idx = t * 4 + i;
        v[i] = (idx < B) ? bsum[idx] : 0;
        tsum += v[i];
    }
    s[t] = tsum; __syncthreads();
    for (int off = 1; off < 256; off <<= 1) {
        int x = (t >= off) ? s[t - off] : 0;
        __syncthreads();
        s[t] += x;
        __syncthreads();
    }
    int run = s[t] - tsum;
    #pragma unroll
    for (int i = 0; i < 4; ++i) {
        int idx = t * 4 + i;
        if (idx < B) bsum[idx] = run;
        run += v[i];
    }
}

__global__ __launch_bounds__(256) void scan_add_kernel(
    int* __restrict__ start, int* __restrict__ cursor,
    const int* __restrict__ bsum, int N)
{
    int i = blockIdx.x * 256 + threadIdx.x;
    if (i < N) {
        int v = start[i] + bsum[i >> 10];
        start[i]  = v;
        cursor[i] = v;
    }
}

__global__ __launch_bounds__(256) void fill_kernel(
    const int* __restrict__ src, const int* __restrict__ dst,
    int* __restrict__ cursor, int* __restrict__ eidx, int E)
{
    int i = blockIdx.x * 256 + threadIdx.x;
    if (i < E) {
        int d = dst[i];
        int p = atomicAdd(&cursor[d], 1);
        eidx[p] = src[i];
    }
}

// ======================= gather-based segment sum ===========================
// msg[r] = sum_{j in CSR[r]} h[eidx[j]]   (32 lanes per row, 8 rows/block)
__global__ __launch_bounds__(256) void gather_kernel(
    const bf16t* __restrict__ h, const int* __restrict__ eidx,
    const int* __restrict__ start, const int* __restrict__ deg,
    bf16t* __restrict__ msg, int N)
{
    int r = blockIdx.x * 8 + (threadIdx.x >> 5);
    if (r >= N) return;
    int lane = threadIdx.x & 31;
    int s0 = start[r], cnt = deg[r];
    float4 acc = make_float4(0.f, 0.f, 0.f, 0.f);
    for (int j = s0; j < s0 + cnt; ++j) {
        int s = eidx[j];
        float4 v = ld4(&h[(size_t)s * HDIM + lane * 4]);
        acc.x += v.x; acc.y += v.y; acc.z += v.z; acc.w += v.w;
    }
    st4(&msg[(size_t)r * HDIM + lane * 4], acc);
}

// ======================= weight repack (MFMA A-fragment order) ==============
// GEMM form: z1^T = W1^T @ act^T.  A-tile (mt,kc): lane l, elem j holds
//   W1[kc*32 + (l>>4)*8 + j][mt*16 + (l&15)]
// stored at W1P[((kc*8 + mt)*64 + l)*8 + j].
__global__ __launch_bounds__(256) void pack_w1_kernel(
    const float* __restrict__ W1t, bf16t* __restrict__ W1P, int total)
{
    int q = blockIdx.x * 256 + threadIdx.x;
    if (q >= total) return;
    int L = q >> 15;                 // 32768 per level
    int r = q & 32767;
    int j = r & 7, l = (r >> 3) & 63, mt = (r >> 9) & 7, kc = (r >> 12) & 7;
    float v = W1t[(size_t)L * 2 * HDIM * HDIM +
                  (size_t)(kc * 32 + ((l >> 4) & 3) * 8 + j) * HDIM + mt * 16 + (l & 15)];
    *(unsigned short*)&W1P[q] = f2bf(v);
}

__global__ __launch_bounds__(256) void pack_w2_kernel(
    const float* __restrict__ W2t, bf16t* __restrict__ W2P, int total)
{
    int q = blockIdx.x * 256 + threadIdx.x;
    if (q >= total) return;
    int L = q >> 14;                 // 16384 per level
    int r = q & 16383;
    int j = r & 7, l = (r >> 3) & 63, mt = (r >> 9) & 7, kc = (r >> 12) & 3;
    float v = W2t[(size_t)L * HDIM * HDIM +
                  (size_t)(kc * 32 + ((l >> 4) & 3) * 8 + j) * HDIM + mt * 16 + (l & 15)];
    *(unsigned short*)&W2P[q] = f2bf(v);
}

// ======================= MFMA combine =======================================
// z1 = relu([hd|msg] @ W1 + b1); hd = relu(z1 @ W2 + b2), all via
// transposed MFMA: z1^T = W1P-frags x act-frags;  out^T = W2P-frags x z1-frags.
// Block: 64 rows, 4 waves; wave handles feature range [wave*32, wave*32+32).
#define ACT_STRIDE 264   // 256 + 8 bf16 pad
#define Z_STRIDE   136   // 128 + 8 bf16 pad
__global__ __launch_bounds__(256) void combine_mfma_kernel(
    bf16t* __restrict__ hd, const bf16t* __restrict__ msg,
    const bf16t* __restrict__ W1P, const float* __restrict__ b1,
    const bf16t* __restrict__ W2P, const float* __restrict__ b2, int N)
{
    __shared__ bf16t act_s[64 * ACT_STRIDE];   // 33,792 B
    __shared__ bf16t z_s[64 * Z_STRIDE];       // 17,408 B   (51,200 total)

    const int tid  = threadIdx.x;
    const int row0 = blockIdx.x * 64;
    const int wave = tid >> 6, lane = tid & 63;
    const int l15 = lane & 15, l16 = lane >> 4;

    // ---- stage activations: act_s[r][0:128]=hd row, [128:256]=msg row ----
    #pragma unroll
    for (int i = 0; i < 4; ++i) {
        int f = tid + i * 256;               // 16B segment idx in 64x(128bf16)
        int r = f >> 4, seg = f & 15;
        int row = row0 + r; if (row >= N) row = N - 1;
        *(float4*)&act_s[r * ACT_STRIDE + seg * 8] =
            *(const float4*)&hd[(size_t)row * HDIM + seg * 8];
        *(float4*)&act_s[r * ACT_STRIDE + 128 + seg * 8] =
            *(const float4*)&msg[(size_t)row * HDIM + seg * 8];
    }
    __syncthreads();

    // ---- GEMM1: K=256 (8 chunks), per wave 2 m-tiles x 4 n-tiles ----
    f32x4 acc1[2][4];
    #pragma unroll
    for (int m = 0; m < 2; ++m)
        #pragma unroll
        for (int n = 0; n < 4; ++n)
            #pragma unroll
            for (int i = 0; i < 4; ++i) acc1[m][n][i] = 0.f;

    for (int kc = 0; kc < 8; ++kc) {
        bf16x8 a[2], b[4];
        #pragma unroll
        for (int m = 0; m < 2; ++m) {
            int mt = wave * 2 + m;
            a[m] = *(const bf16x8*)&W1P[((kc * 8 + mt) * 64 + lane) * 8];
        }
        #pragma unroll
        for (int n = 0; n < 4; ++n)
            b[n] = *(const bf16x8*)&act_s[(n * 16 + l15) * ACT_STRIDE + kc * 32 + l16 * 8];
        #pragma unroll
        for (int m = 0; m < 2; ++m)
            #pragma unroll
            for (int n = 0; n < 4; ++n)
                acc1[m][n] = __builtin_amdgcn_mfma_f32_16x16x32_bf16(a[m], b[n], acc1[m][n], 0, 0, 0);
    }

    // ---- z1 = relu(acc1 + b1) -> z_s[row][feat] (bf16) ----
    #pragma unroll
    for (int m = 0; m < 2; ++m) {
        int mt = wave * 2 + m;
        float4 bb = *(const float4*)&b1[mt * 16 + l16 * 4];
        #pragma unroll
        for (int n = 0; n < 4; ++n) {
            int zrow = n * 16 + l15;
            ushort4 u;
            u.x = f2bf(reluf(acc1[m][n][0] + bb.x));
            u.y = f2bf(reluf(acc1[m][n][1] + bb.y));
            u.z = f2bf(reluf(acc1[m][n][2] + bb.z));
            u.w = f2bf(reluf(acc1[m][n][3] + bb.w));
            *(ushort4*)&z_s[zrow * Z_STRIDE + mt * 16 + l16 * 4] = u;
        }
    }
    __syncthreads();

    // ---- GEMM2: K=128 (4 chunks) ----
    f32x4 acc2[2][4];
    #pragma unroll
    for (int m = 0; m < 2; ++m)
        #pragma unroll
        for (int n = 0; n < 4; ++n)
            #pragma unroll
            for (int i = 0; i < 4; ++i) acc2[m][n][i] = 0.f;

    for (int kc = 0; kc < 4; ++kc) {
        bf16x8 a[2], b[4];
        #pragma unroll
        for (int m = 0; m < 2; ++m) {
            int mt = wave * 2 + m;
            a[m] = *(const bf16x8*)&W2P[((kc * 8 + mt) * 64 + lane) * 8];
        }
        #pragma unroll
        for (int n = 0; n < 4; ++n)
            b[n] = *(const bf16x8*)&z_s[(n * 16 + l15) * Z_STRIDE + kc * 32 + l16 * 8];
        #pragma unroll
        for (int m = 0; m < 2; ++m)
            #pragma unroll
            for (int n = 0; n < 4; ++n)
                acc2[m][n] = __builtin_amdgcn_mfma_f32_16x16x32_bf16(a[m], b[n], acc2[m][n], 0, 0, 0);
    }

    // ---- out = relu(acc2 + b2) -> hd (in place; block owns its 64 rows) ----
    #pragma unroll
    for (int m = 0; m < 2; ++m) {
        int mt = wave * 2 + m;
        float4 bb = *(const float4*)&b2[mt * 16 + l16 * 4];
        #pragma unroll
        for (int n = 0; n < 4; ++n) {
            int row = row0 + n * 16 + l15;
            if (row < N) {
                ushort4 u;
                u.x = f2bf(reluf(acc2[m][n][0] + bb.x));
                u.y = f2bf(reluf(acc2[m][n][1] + bb.y));
                u.z = f2bf(reluf(acc2[m][n][2] + bb.z));
                u.w = f2bf(reluf(acc2[m][n][3] + bb.w));
                *(ushort4*)&hd[(size_t)row * HDIM + mt * 16 + l16 * 4] = u;
            }
        }
    }
}

// ---------------------------------------------------------------------------
// Final: t1 = relu(h_enc @ Wf1 + bf1) (fp32 out), then rowdot.
// ---------------------------------------------------------------------------
__global__ __launch_bounds__(256) void mlp128_kernel(
    const bf16t* __restrict__ in, const float* __restrict__ W,
    const float* __restrict__ b, float* __restrict__ out, int N)
{
    __shared__ float smem[12544];
    float* a_s = smem;                   // 64x128 stride 132
    float* w_s = smem + 8448;            // 32x128

    const int tid  = threadIdx.x;
    const int row0 = blockIdx.x * 64;
    const int tr = tid >> 4, tc = tid & 15, trow = tr * 4;

    #pragma unroll
    for (int i = 0; i < 8; ++i) {
        int f = tid + i * 256;
        int r = f >> 5, c4 = f & 31;
        float4 v = make_float4(0.f, 0.f, 0.f, 0.f);
        if (row0 + r < N)
            v = ld4(&in[(size_t)(row0 + r) * HDIM + c4 * 4]);
        *(float4*)&a_s[r * 132 + c4 * 4] = v;
    }

    float acc[4][8] = {};
    for (int kc = 0; kc < 4; ++kc) {
        if (kc) __syncthreads();
        #pragma unroll
        for (int i = 0; i < 4; ++i) {
            int f = tid + i * 256;
            int r = f >> 5, c4 = f & 31;
            *(float4*)&w_s[r * HDIM + c4 * 4] =
                *(const float4*)&W[(size_t)(kc * 32 + r) * HDIM + c4 * 4];
        }
        __syncthreads();
        #pragma unroll 2
        for (int k = 0; k < 32; ++k) {
            float av[4];
            #pragma unroll
            for (int r = 0; r < 4; ++r)
                av[r] = a_s[(trow + r) * 132 + kc * 32 + k];
            float4 w0 = *(float4*)&w_s[k * HDIM + tc * 8];
            float4 w1 = *(float4*)&w_s[k * HDIM + tc * 8 + 4];
            float wv[8] = {w0.x, w0.y, w0.z, w0.w, w1.x, w1.y, w1.z, w1.w};
            #pragma unroll
            for (int r = 0; r < 4; ++r)
                #pragma unroll
                for (int c = 0; c < 8; ++c)
                    acc[r][c] += av[r] * wv[c];
        }
    }

    float4 ba = *(const float4*)&b[tc * 8];
    float4 bb = *(const float4*)&b[tc * 8 + 4];
    float bv[8] = {ba.x, ba.y, ba.z, ba.w, bb.x, bb.y, bb.z, bb.w};
    #pragma unroll
    for (int r = 0; r < 4; ++r) {
        int row = row0 + trow + r;
        if (row < N) {
            float4 o0 = make_float4(reluf(acc[r][0] + bv[0]), reluf(acc[r][1] + bv[1]),
                                    reluf(acc[r][2] + bv[2]), reluf(acc[r][3] + bv[3]));
            float4 o1 = make_float4(reluf(acc[r][4] + bv[4]), reluf(acc[r][5] + bv[5]),
                                    reluf(acc[r][6] + bv[6]), reluf(acc[r][7] + bv[7]));
            *(float4*)&out[(size_t)row * HDIM + tc * 8]     = o0;
            *(float4*)&out[(size_t)row * HDIM + tc * 8 + 4] = o1;
        }
    }
}

__global__ __launch_bounds__(256) void rowdot_kernel(
    const float* __restrict__ t1, const float* __restrict__ w,
    const float* __restrict__ b, float* __restrict__ out, int N)
{
    __shared__ float w_s[HDIM];
    if (threadIdx.x < 32)
        *(float4*)&w_s[threadIdx.x * 4] = *(const float4*)&w[threadIdx.x * 4];
    __syncthreads();
    int row = blockIdx.x * 256 + threadIdx.x;
    if (row >= N) return;
    float acc = 0.f;
    #pragma unroll
    for (int k4 = 0; k4 < 32; ++k4) {
        float4 v = *(const float4*)&t1[(size_t)row * HDIM + k4 * 4];
        acc += v.x * w_s[k4 * 4] + v.y * w_s[k4 * 4 + 1]
             + v.z * w_s[k4 * 4 + 2] + v.w * w_s[k4 * 4 + 3];
    }
    out[row] = acc + b[0];
}

__global__ __launch_bounds__(256) void sentinel_kernel(float* out, int n, float val)
{
    int i = blockIdx.x * 256 + threadIdx.x;
    if (i < n) out[i] = (i == 0) ? val : 0.f;
}

// ---------------------------------------------------------------------------
static void build_csr(const int* src, const int* dst, int E, int N,
                      int* deg, int* start, int* cursor, int* eidx, int* bsum,
                      hipStream_t stream)
{
    const dim3 blk(256);
    hipMemsetAsync(deg, 0, (size_t)N * sizeof(int), stream);
    hist_kernel<<<dim3((E + 255) / 256), blk, 0, stream>>>(dst, deg, E);
    int B = (N + 1023) / 1024;
    scan_blocks_kernel<<<dim3(B), blk, 0, stream>>>(deg, start, bsum, N);
    scan_top_kernel<<<dim3(1), blk, 0, stream>>>(bsum, B);
    scan_add_kernel<<<dim3((N + 255) / 256), blk, 0, stream>>>(start, cursor, bsum, N);
    fill_kernel<<<dim3((E + 255) / 256), blk, 0, stream>>>(src, dst, cursor, eidx, E);
}

extern "C" void kernel_launch(void* const* d_in, const int* in_sizes, int n_in,
                              void* d_out, int out_size, void* d_ws, size_t ws_size,
                              hipStream_t stream)
{
    const float* x_col  = (const float*)d_in[0];
    const float* x_filt = (const float*)d_in[1];
    const float* x_pred = (const float*)d_in[2];
    const float* x_scan = (const float*)d_in[3];
    const float* x_join = (const float*)d_in[4];
    const float* x_enc  = (const float*)d_in[5];
    const float* W_enc  = (const float*)d_in[6];
    const float* b_enc  = (const float*)d_in[7];
    const float* W1t    = (const float*)d_in[8];
    const float* b1t    = (const float*)d_in[9];
    const float* W2t    = (const float*)d_in[10];
    const float* b2t    = (const float*)d_in[11];
    const float* Wf1    = (const float*)d_in[12];
    const float* bf1    = (const float*)d_in[13];
    const float* Wf2    = (const float*)d_in[14];
    const float* bf2    = (const float*)d_in[15];
    const int* src_cf = (const int*)d_in[16];
    const int* dst_cf = (const int*)d_in[17];
    const int* src_fp = (const int*)d_in[18];
    const int* dst_fp = (const int*)d_in[19];
    const int* src_ps = (const int*)d_in[20];
    const int* dst_ps = (const int*)d_in[21];
    const int* src_sj = (const int*)d_in[22];
    const int* dst_sj = (const int*)d_in[23];
    const int* src_je = (const int*)d_in[24];
    const int* dst_je = (const int*)d_in[25];

    const int N_COL  = in_sizes[0] / FIN;
    const int N_FILT = in_sizes[1] / FIN;
    const int N_PRED = in_sizes[2] / FIN;
    const int N_SCAN = in_sizes[3] / FIN;
    const int N_JOIN = in_sizes[4] / FIN;
    const int N_ENC  = in_sizes[5] / FIN;
    const int E_CF = in_sizes[16];
    const int E_FP = in_sizes[18];
    const int E_PS = in_sizes[20];
    const int E_SJ = in_sizes[22];
    const int E_JE = in_sizes[24];

    // ---- workspace layout ----
    // msg region: max dst-level bf16 msg; also aliases t1 (fp32) at the end.
    size_t Mf = 0;
    {
        size_t c;
        c = (size_t)N_FILT * HDIM; if (c > Mf) Mf = c;
        c = (size_t)N_PRED * HDIM; if (c > Mf) Mf = c;
        c = (size_t)N_SCAN * HDIM; if (c > Mf) Mf = c;
        c = (size_t)N_JOIN * HDIM; if (c > Mf) Mf = c;
        c = (size_t)N_ENC  * HDIM; if (c > Mf) Mf = c;
    }
    // H region (bf16): time-shared by h_col, then {h_filt,h_pred,...}
    size_t Hf = (size_t)N_COL * HDIM;
    { size_t c = (size_t)(N_FILT + N_PRED) * HDIM; if (c > Hf) Hf = c; }
    { size_t c = (size_t)(N_SCAN + N_JOIN + N_ENC + N_PRED) * HDIM; if (c > Hf) Hf = c; }

    int maxN = N_FILT;
    if (N_PRED > maxN) maxN = N_PRED;
    if (N_SCAN > maxN) maxN = N_SCAN;
    if (N_JOIN > maxN) maxN = N_JOIN;
    if (N_ENC  > maxN) maxN = N_ENC;
    int maxE = E_CF;
    if (E_FP > maxE) maxE = E_FP;
    if (E_PS > maxE) maxE = E_PS;
    if (E_SJ > maxE) maxE = E_SJ;
    if (E_JE > maxE) maxE = E_JE;

    const int W1P_TOT = 5 * 2 * HDIM * HDIM;   // 163840 bf16
    const int W2P_TOT = 5 * HDIM * HDIM;       //  81920 bf16

    size_t msgB  = Mf * 2;
    size_t t1B   = (size_t)N_ENC * HDIM * 4;
    if (t1B > msgB) msgB = t1B;
    msgB = (msgB + 255) & ~(size_t)255;
    size_t hB    = ((Hf * 2) + 255) & ~(size_t)255;
    size_t intB  = (((size_t)maxN * 4) + 255) & ~(size_t)255;
    size_t eidxB = (((size_t)maxE * 4) + 255) & ~(size_t)255;
    size_t wpB   = (((size_t)(W1P_TOT + W2P_TOT) * 2) + 255) & ~(size_t)255;
    size_t need  = msgB + hB + 3 * intB + eidxB + wpB + 8192;

    if (!d_ws || ws_size < need) {
        float val = 1.0e6f + (float)(ws_size >> 20);
        sentinel_kernel<<<dim3((out_size + 255) / 256), dim3(256), 0, stream>>>(
            (float*)d_out, out_size, val);
        return;
    }

    char* base = (char*)d_ws;
    bf16t* msg  = (bf16t*)base;                       base += msgB;
    bf16t* H    = (bf16t*)base;                       base += hB;
    int* deg    = (int*)base;                         base += intB;
    int* start  = (int*)base;                         base += intB;
    int* cursor = (int*)base;                         base += intB;
    int* eidx   = (int*)base;                         base += eidxB;
    bf16t* W1P  = (bf16t*)base;                       base += (size_t)W1P_TOT * 2;
    bf16t* W2P  = (bf16t*)base;                       base += (size_t)W2P_TOT * 2;
    int* bsum   = (int*)(((size_t)base + 255) & ~(size_t)255);

    bf16t* h_col  = H;                                 // dead after gather0
    bf16t* h_filt = H;
    bf16t* h_pred = H + (size_t)N_FILT * HDIM;
    bf16t* h_scan = H;                                 // h_filt dead by then
    bf16t* h_join = H + (size_t)N_SCAN * HDIM;
    bf16t* h_enc  = H + (size_t)(N_SCAN + N_JOIN) * HDIM;
    float* t1     = (float*)msg;                       // msg dead by then

    const dim3 blk(256);

    // ---- weight repack (bf16, MFMA fragment order) ----
    pack_w1_kernel<<<dim3((W1P_TOT + 255) / 256), blk, 0, stream>>>(W1t, W1P, W1P_TOT);
    pack_w2_kernel<<<dim3((W2P_TOT + 255) / 256), blk, 0, stream>>>(W2t, W2P, W2P_TOT);

    // ---- level 0: column -> filter ----
    build_csr(src_cf, dst_cf, E_CF, N_FILT, deg, start, cursor, eidx, bsum, stream);
    enc_kernel<<<dim3((N_COL + 63) / 64), blk, 0, stream>>>(
        x_col, W_enc, b_enc, h_col, N_COL);
    gather_kernel<<<dim3((N_FILT + 7) / 8), blk, 0, stream>>>(
        h_col, eidx, start, deg, msg, N_FILT);
    enc_kernel<<<dim3((N_FILT + 63) / 64), blk, 0, stream>>>(      // overwrites h_col region
        x_filt, W_enc + 1 * FIN * HDIM, b_enc + 1 * HDIM, h_filt, N_FILT);
    combine_mfma_kernel<<<dim3((N_FILT + 63) / 64), blk, 0, stream>>>(
        h_filt, msg, W1P, b1t, W2P, b2t, N_FILT);

    // ---- level 1: filter -> pred ----
    build_csr(src_fp, dst_fp, E_FP, N_PRED, deg, start, cursor, eidx, bsum, stream);
    gather_kernel<<<dim3((N_PRED + 7) / 8), blk, 0, stream>>>(
        h_filt, eidx, start, deg, msg, N_PRED);
    enc_kernel<<<dim3((N_PRED + 63) / 64), blk, 0, stream>>>(
        x_pred, W_enc + 2 * FIN * HDIM, b_enc + 2 * HDIM, h_pred, N_PRED);
    combine_mfma_kernel<<<dim3((N_PRED + 63) / 64), blk, 0, stream>>>(
        h_pred, msg, W1P + 1 * 2 * HDIM * HDIM, b1t + 1 * HDIM,
        W2P + 1 * HDIM * HDIM, b2t + 1 * HDIM, N_PRED);

    // ---- level 2: pred -> scan ----
    build_csr(src_ps, dst_ps, E_PS, N_SCAN, deg, start, cursor, eidx, bsum, stream);
    gather_kernel<<<dim3((N_SCAN + 7) / 8), blk, 0, stream>>>(
        h_pred, eidx, start, deg, msg, N_SCAN);
    enc_kernel<<<dim3((N_SCAN + 63) / 64), blk, 0, stream>>>(
        x_scan, W_enc + 3 * FIN * HDIM, b_enc + 3 * HDIM, h_scan, N_SCAN);
    combine_mfma_kernel<<<dim3((N_SCAN + 63) / 64), blk, 0, stream>>>(
        h_scan, msg, W1P + 2 * 2 * HDIM * HDIM, b1t + 2 * HDIM,
        W2P + 2 * HDIM * HDIM, b2t + 2 * HDIM, N_SCAN);

    // ---- level 3: scan -> join ----
    build_csr(src_sj, dst_sj, E_SJ, N_JOIN, deg, start, cursor, eidx, bsum, stream);
    gather_kernel<<<dim3((N_JOIN + 7) / 8), blk, 0, stream>>>(
        h_scan, eidx, start, deg, msg, N_JOIN);
    enc_kernel<<<dim3((N_JOIN + 63) / 64), blk, 0, stream>>>(
        x_join, W_enc + 4 * FIN * HDIM, b_enc + 4 * HDIM, h_join, N_JOIN);
    combine_mfma_kernel<<<dim3((N_JOIN + 63) / 64), blk, 0, stream>>>(
        h_join, msg, W1P + 3 * 2 * HDIM * HDIM, b1t + 3 * HDIM,
        W2P + 3 * HDIM * HDIM, b2t + 3 * HDIM, N_JOIN);

    // ---- level 4: join -> encode ----
    build_csr(src_je, dst_je, E_JE, N_ENC, deg, start, cursor, eidx, bsum, stream);
    gather_kernel<<<dim3((N_ENC + 7) / 8), blk, 0, stream>>>(
        h_join, eidx, start, deg, msg, N_ENC);
    enc_kernel<<<dim3((N_ENC + 63) / 64), blk, 0, stream>>>(
        x_enc, W_enc + 5 * FIN * HDIM, b_enc + 5 * HDIM, h_enc, N_ENC);
    combine_mfma_kernel<<<dim3((N_ENC + 63) / 64), blk, 0, stream>>>(
        h_enc, msg, W1P + 4 * 2 * HDIM * HDIM, b1t + 4 * HDIM,
        W2P + 4 * HDIM * HDIM, b2t + 4 * HDIM, N_ENC);

    // ---- final MLP ----
    mlp128_kernel<<<dim3((N_ENC + 63) / 64), blk, 0, stream>>>(h_enc, Wf1, bf1, t1, N_ENC);
    rowdot_kernel<<<dim3((N_ENC + 255) / 256), blk, 0, stream>>>(t1, Wf2, bf2, (float*)d_out, N_ENC);
}

// Round 5
// 576.959 us; speedup vs baseline: 3.8146x; 1.3995x over previous
//
#include <hip/hip_runtime.h>
#include <hip/hip_bf16.h>

#define HDIM 128
#define FIN  32

typedef __hip_bfloat16 bf16t;
using bf16x8 = __attribute__((ext_vector_type(8))) short;
using f32x4  = __attribute__((ext_vector_type(4))) float;

__device__ __forceinline__ float reluf(float x) { return x > 0.f ? x : 0.f; }

__device__ __forceinline__ unsigned short f2bf(float f) {
    unsigned int b = __float_as_uint(f);
    b += 0x7FFFu + ((b >> 16) & 1u);       // round-to-nearest-even
    return (unsigned short)(b >> 16);
}
__device__ __forceinline__ float bf2f(unsigned short u) {
    return __uint_as_float(((unsigned int)u) << 16);
}

__device__ __forceinline__ float4 ld4(const bf16t* p) {
    ushort4 u = *(const ushort4*)p;
    return make_float4(bf2f(u.x), bf2f(u.y), bf2f(u.z), bf2f(u.w));
}
__device__ __forceinline__ void st4(bf16t* p, float4 v) {
    ushort4 u;
    u.x = f2bf(v.x); u.y = f2bf(v.y); u.z = f2bf(v.z); u.w = f2bf(v.w);
    *(ushort4*)p = u;
}

// ======================= CSR construction ===================================
__global__ __launch_bounds__(256) void hist_kernel(
    const int* __restrict__ dst, int* __restrict__ deg, int E)
{
    int i = blockIdx.x * 256 + threadIdx.x;
    if (i < E) atomicAdd(&deg[dst[i]], 1);
}

__global__ __launch_bounds__(256) void scan_blocks_kernel(
    const int* __restrict__ deg, int* __restrict__ start,
    int* __restrict__ bsum, int N)
{
    __shared__ int s[256];
    const int t = threadIdx.x;
    const int base = blockIdx.x * 1024;
    int v[4], tsum = 0;
    #pragma unroll
    for (int i = 0; i < 4; ++i) {
        int idx = base + t * 4 + i;
        v[i] = (idx < N) ? deg[idx] : 0;
        tsum += v[i];
    }
    s[t] = tsum; __syncthreads();
    for (int off = 1; off < 256; off <<= 1) {
        int x = (t >= off) ? s[t - off] : 0;
        __syncthreads();
        s[t] += x;
        __syncthreads();
    }
    if (t == 255) bsum[blockIdx.x] = s[255];
    int run = s[t] - tsum;
    #pragma unroll
    for (int i = 0; i < 4; ++i) {
        int idx = base + t * 4 + i;
        if (idx < N) start[idx] = run;
        run += v[i];
    }
}

__global__ __launch_bounds__(256) void scan_top_kernel(int* __restrict__ bsum, int B)
{
    __shared__ int s[256];
    const int t = threadIdx.x;
    int v[4], tsum = 0;
    #pragma unroll
    for (int i = 0; i < 4; ++i) {
        int idx = t * 4 + i;
        v[i] = (idx < B) ? bsum[idx] : 0;
        tsum += v[i];
    }
    s[t] = tsum; __syncthreads();
    for (int off = 1; off < 256; off <<= 1) {
        int x = (t >= off) ? s[t - off] : 0;
        __syncthreads();
        s[t] += x;
        __syncthreads();
    }
    int run = s[t] - tsum;
    #pragma unroll
    for (int i = 0; i < 4; ++i) {
        int idx = t * 4 + i;
        if (idx < B) bsum[idx] = run;
        run += v[i];
    }
}

__global__ __launch_bounds__(256) void scan_add_kernel(
    int* __restrict__ start, int* __restrict__ cursor,
    const int* __restrict__ bsum, int N)
{
    int i = blockIdx.x * 256 + threadIdx.x;
    if (i < N) {
        int v = start[i] + bsum[i >> 10];
        start[i]  = v;
        cursor[i] = v;
    }
}

__global__ __launch_bounds__(256) void fill_kernel(
    const int* __restrict__ src, const int* __restrict__ dst,
    int* __restrict__ cursor, int* __restrict__ eidx, int E)
{
    int i = blockIdx.x * 256 + threadIdx.x;
    if (i < E) {
        int d = dst[i];
        int p = atomicAdd(&cursor[d], 1);
        eidx[p] = src[i];
    }
}

// ======================= gather-based segment sum ===========================
__global__ __launch_bounds__(256) void gather_kernel(
    const bf16t* __restrict__ h, const int* __restrict__ eidx,
    const int* __restrict__ start, const int* __restrict__ deg,
    bf16t* __restrict__ msg, int N)
{
    int r = blockIdx.x * 8 + (threadIdx.x >> 5);
    if (r >= N) return;
    int lane = threadIdx.x & 31;
    int s0 = start[r], cnt = deg[r];
    float4 acc = make_float4(0.f, 0.f, 0.f, 0.f);
    for (int j = s0; j < s0 + cnt; ++j) {
        int s = eidx[j];
        float4 v = ld4(&h[(size_t)s * HDIM + lane * 4]);
        acc.x += v.x; acc.y += v.y; acc.z += v.z; acc.w += v.w;
    }
    st4(&msg[(size_t)r * HDIM + lane * 4], acc);
}

// ======================= weight repack (MFMA A-fragment order) ==============
// A-frag: lane l, elem j holds A[m = mt*16 + (l&15)][k = kc*32 + (l>>4)*8 + j]
// with A = W^T, i.e. value W[k][m], stored at P[((kc*NMT + mt)*64 + l)*8 + j].
__global__ __launch_bounds__(256) void pack_w1_kernel(
    const float* __restrict__ W1t, bf16t* __restrict__ W1P, int total)
{
    int q = blockIdx.x * 256 + threadIdx.x;
    if (q >= total) return;
    int L = q >> 15;                 // 32768 per level (K=256, 8 kc x 8 mt)
    int r = q & 32767;
    int j = r & 7, l = (r >> 3) & 63, mt = (r >> 9) & 7, kc = (r >> 12) & 7;
    float v = W1t[(size_t)L * 2 * HDIM * HDIM +
                  (size_t)(kc * 32 + ((l >> 4) & 3) * 8 + j) * HDIM + mt * 16 + (l & 15)];
    *(unsigned short*)&W1P[q] = f2bf(v);
}

__global__ __launch_bounds__(256) void pack_w2_kernel(
    const float* __restrict__ W2t, bf16t* __restrict__ W2P, int total)
{
    int q = blockIdx.x * 256 + threadIdx.x;
    if (q >= total) return;
    int L = q >> 14;                 // 16384 per level (K=128, 4 kc x 8 mt)
    int r = q & 16383;
    int j = r & 7, l = (r >> 3) & 63, mt = (r >> 9) & 7, kc = (r >> 12) & 3;
    float v = W2t[(size_t)L * HDIM * HDIM +
                  (size_t)(kc * 32 + ((l >> 4) & 3) * 8 + j) * HDIM + mt * 16 + (l & 15)];
    *(unsigned short*)&W2P[q] = f2bf(v);
}

// K=32 encoder weights: 6 encoders x (1 kc x 8 mt x 64 l x 8 j) = 6*4096
__global__ __launch_bounds__(256) void pack_we_kernel(
    const float* __restrict__ We, bf16t* __restrict__ WeP, int total)
{
    int q = blockIdx.x * 256 + threadIdx.x;
    if (q >= total) return;
    int enc = q >> 12;
    int r = q & 4095;
    int j = r & 7, l = (r >> 3) & 63, mt = (r >> 9) & 7;
    int k = ((l >> 4) & 3) * 8 + j;
    float v = We[(size_t)enc * FIN * HDIM + (size_t)k * HDIM + mt * 16 + (l & 15)];
    *(unsigned short*)&WeP[q] = f2bf(v);
}

// ======================= MFMA encoder =======================================
// h = relu(x @ W + b) via h^T = W^T x^T.  64 rows/block, 4 waves,
// wave covers feats [wave*32, wave*32+32), K=32 in one MFMA chunk.
__global__ __launch_bounds__(256) void enc_mfma_kernel(
    const float* __restrict__ x, const bf16t* __restrict__ WP,
    const float* __restrict__ b, bf16t* __restrict__ h, int N)
{
    __shared__ bf16t x_s[64 * 36];           // 4.6 KB, stride-36 pad
    const int tid  = threadIdx.x;
    const int row0 = blockIdx.x * 64;
    const int wave = tid >> 6, lane = tid & 63;
    const int l15 = lane & 15, l16 = lane >> 4;

    #pragma unroll
    for (int i = 0; i < 2; ++i) {
        int f = tid + i * 256;               // float4 idx in 64x32
        int r = f >> 3, c4 = f & 7;
        int row = row0 + r; if (row >= N) row = N - 1;
        float4 v = *(const float4*)&x[(size_t)row * FIN + c4 * 4];
        ushort4 u;
        u.x = f2bf(v.x); u.y = f2bf(v.y); u.z = f2bf(v.z); u.w = f2bf(v.w);
        *(ushort4*)&x_s[r * 36 + c4 * 4] = u;
    }
    __syncthreads();

    f32x4 acc[2][4];
    #pragma unroll
    for (int m = 0; m < 2; ++m)
        #pragma unroll
        for (int n = 0; n < 4; ++n)
            #pragma unroll
            for (int i = 0; i < 4; ++i) acc[m][n][i] = 0.f;

    bf16x8 a[2], bb[4];
    #pragma unroll
    for (int m = 0; m < 2; ++m)
        a[m] = *(const bf16x8*)&WP[(((wave * 2 + m)) * 64 + lane) * 8];
    #pragma unroll
    for (int n = 0; n < 4; ++n)
        bb[n] = *(const bf16x8*)&x_s[(n * 16 + l15) * 36 + l16 * 8];
    #pragma unroll
    for (int m = 0; m < 2; ++m)
        #pragma unroll
        for (int n = 0; n < 4; ++n)
            acc[m][n] = __builtin_amdgcn_mfma_f32_16x16x32_bf16(a[m], bb[n], acc[m][n], 0, 0, 0);

    #pragma unroll
    for (int m = 0; m < 2; ++m) {
        int mt = wave * 2 + m;
        float4 bv = *(const float4*)&b[mt * 16 + l16 * 4];
        #pragma unroll
        for (int n = 0; n < 4; ++n) {
            int row = row0 + n * 16 + l15;
            if (row < N) {
                ushort4 u;
                u.x = f2bf(reluf(acc[m][n][0] + bv.x));
                u.y = f2bf(reluf(acc[m][n][1] + bv.y));
                u.z = f2bf(reluf(acc[m][n][2] + bv.z));
                u.w = f2bf(reluf(acc[m][n][3] + bv.w));
                *(ushort4*)&h[(size_t)row * HDIM + mt * 16 + l16 * 4] = u;
            }
        }
    }
}

// ======================= MFMA combine =======================================
#define ACT_STRIDE 264   // 256 + 8 bf16 pad
#define Z_STRIDE   136   // 128 + 8 bf16 pad
__global__ __launch_bounds__(256) void combine_mfma_kernel(
    bf16t* __restrict__ hd, const bf16t* __restrict__ msg,
    const bf16t* __restrict__ W1P, const float* __restrict__ b1,
    const bf16t* __restrict__ W2P, const float* __restrict__ b2, int N)
{
    __shared__ bf16t act_s[64 * ACT_STRIDE];   // 33,792 B
    __shared__ bf16t z_s[64 * Z_STRIDE];       // 17,408 B

    const int tid  = threadIdx.x;
    const int row0 = blockIdx.x * 64;
    const int wave = tid >> 6, lane = tid & 63;
    const int l15 = lane & 15, l16 = lane >> 4;

    #pragma unroll
    for (int i = 0; i < 4; ++i) {
        int f = tid + i * 256;
        int r = f >> 4, seg = f & 15;
        int row = row0 + r; if (row >= N) row = N - 1;
        *(float4*)&act_s[r * ACT_STRIDE + seg * 8] =
            *(const float4*)&hd[(size_t)row * HDIM + seg * 8];
        *(float4*)&act_s[r * ACT_STRIDE + 128 + seg * 8] =
            *(const float4*)&msg[(size_t)row * HDIM + seg * 8];
    }
    __syncthreads();

    f32x4 acc1[2][4];
    #pragma unroll
    for (int m = 0; m < 2; ++m)
        #pragma unroll
        for (int n = 0; n < 4; ++n)
            #pragma unroll
            for (int i = 0; i < 4; ++i) acc1[m][n][i] = 0.f;

    for (int kc = 0; kc < 8; ++kc) {
        bf16x8 a[2], b[4];
        #pragma unroll
        for (int m = 0; m < 2; ++m) {
            int mt = wave * 2 + m;
            a[m] = *(const bf16x8*)&W1P[((kc * 8 + mt) * 64 + lane) * 8];
        }
        #pragma unroll
        for (int n = 0; n < 4; ++n)
            b[n] = *(const bf16x8*)&act_s[(n * 16 + l15) * ACT_STRIDE + kc * 32 + l16 * 8];
        #pragma unroll
        for (int m = 0; m < 2; ++m)
            #pragma unroll
            for (int n = 0; n < 4; ++n)
                acc1[m][n] = __builtin_amdgcn_mfma_f32_16x16x32_bf16(a[m], b[n], acc1[m][n], 0, 0, 0);
    }

    #pragma unroll
    for (int m = 0; m < 2; ++m) {
        int mt = wave * 2 + m;
        float4 bb = *(const float4*)&b1[mt * 16 + l16 * 4];
        #pragma unroll
        for (int n = 0; n < 4; ++n) {
            int zrow = n * 16 + l15;
            ushort4 u;
            u.x = f2bf(reluf(acc1[m][n][0] + bb.x));
            u.y = f2bf(reluf(acc1[m][n][1] + bb.y));
            u.z = f2bf(reluf(acc1[m][n][2] + bb.z));
            u.w = f2bf(reluf(acc1[m][n][3] + bb.w));
            *(ushort4*)&z_s[zrow * Z_STRIDE + mt * 16 + l16 * 4] = u;
        }
    }
    __syncthreads();

    f32x4 acc2[2][4];
    #pragma unroll
    for (int m = 0; m < 2; ++m)
        #pragma unroll
        for (int n = 0; n < 4; ++n)
            #pragma unroll
            for (int i = 0; i < 4; ++i) acc2[m][n][i] = 0.f;

    for (int kc = 0; kc < 4; ++kc) {
        bf16x8 a[2], b[4];
        #pragma unroll
        for (int m = 0; m < 2; ++m) {
            int mt = wave * 2 + m;
            a[m] = *(const bf16x8*)&W2P[((kc * 8 + mt) * 64 + lane) * 8];
        }
        #pragma unroll
        for (int n = 0; n < 4; ++n)
            b[n] = *(const bf16x8*)&z_s[(n * 16 + l15) * Z_STRIDE + kc * 32 + l16 * 8];
        #pragma unroll
        for (int m = 0; m < 2; ++m)
            #pragma unroll
            for (int n = 0; n < 4; ++n)
                acc2[m][n] = __builtin_amdgcn_mfma_f32_16x16x32_bf16(a[m], b[n], acc2[m][n], 0, 0, 0);
    }

    #pragma unroll
    for (int m = 0; m < 2; ++m) {
        int mt = wave * 2 + m;
        float4 bb = *(const float4*)&b2[mt * 16 + l16 * 4];
        #pragma unroll
        for (int n = 0; n < 4; ++n) {
            int row = row0 + n * 16 + l15;
            if (row < N) {
                ushort4 u;
                u.x = f2bf(reluf(acc2[m][n][0] + bb.x));
                u.y = f2bf(reluf(acc2[m][n][1] + bb.y));
                u.z = f2bf(reluf(acc2[m][n][2] + bb.z));
                u.w = f2bf(reluf(acc2[m][n][3] + bb.w));
                *(ushort4*)&hd[(size_t)row * HDIM + mt * 16 + l16 * 4] = u;
            }
        }
    }
}

// ======================= fused final MLP + rowdot ===========================
// out[row] = relu(h_enc[row] @ Wf1 + bf1) . wf2 + bf2
__global__ __launch_bounds__(256) void finale_kernel(
    const bf16t* __restrict__ he, const bf16t* __restrict__ W1P,
    const float* __restrict__ b1, const float* __restrict__ w2,
    const float* __restrict__ b2, float* __restrict__ out, int N)
{
    __shared__ bf16t a_s[64 * Z_STRIDE];     // 17,408 B
    __shared__ float o_s[64];

    const int tid  = threadIdx.x;
    const int row0 = blockIdx.x * 64;
    const int wave = tid >> 6, lane = tid & 63;
    const int l15 = lane & 15, l16 = lane >> 4;

    if (tid < 64) o_s[tid] = 0.f;
    #pragma unroll
    for (int i = 0; i < 4; ++i) {
        int f = tid + i * 256;               // 8B seg idx in 64x(128 bf16)
        int r = f >> 4, seg = f & 15;
        int row = row0 + r; if (row >= N) row = N - 1;
        *(float4*)&a_s[r * Z_STRIDE + seg * 8] =
            *(const float4*)&he[(size_t)row * HDIM + seg * 8];
    }
    __syncthreads();

    f32x4 acc[2][4];
    #pragma unroll
    for (int m = 0; m < 2; ++m)
        #pragma unroll
        for (int n = 0; n < 4; ++n)
            #pragma unroll
            for (int i = 0; i < 4; ++i) acc[m][n][i] = 0.f;

    for (int kc = 0; kc < 4; ++kc) {
        bf16x8 a[2], b[4];
        #pragma unroll
        for (int m = 0; m < 2; ++m) {
            int mt = wave * 2 + m;
            a[m] = *(const bf16x8*)&W1P[((kc * 8 + mt) * 64 + lane) * 8];
        }
        #pragma unroll
        for (int n = 0; n < 4; ++n)
            b[n] = *(const bf16x8*)&a_s[(n * 16 + l15) * Z_STRIDE + kc * 32 + l16 * 8];
        #pragma unroll
        for (int m = 0; m < 2; ++m)
            #pragma unroll
            for (int n = 0; n < 4; ++n)
                acc[m][n] = __builtin_amdgcn_mfma_f32_16x16x32_bf16(a[m], b[n], acc[m][n], 0, 0, 0);
    }

    // epilogue: s[n] = sum over this lane's feats of relu(t1)*wf2
    float s[4] = {0.f, 0.f, 0.f, 0.f};
    #pragma unroll
    for (int m = 0; m < 2; ++m) {
        int mt = wave * 2 + m;
        float4 bb = *(const float4*)&b1[mt * 16 + l16 * 4];
        float4 ww = *(const float4*)&w2[mt * 16 + l16 * 4];
        #pragma unroll
        for (int n = 0; n < 4; ++n) {
            s[n] += reluf(acc[m][n][0] + bb.x) * ww.x
                  + reluf(acc[m][n][1] + bb.y) * ww.y
                  + reluf(acc[m][n][2] + bb.z) * ww.z
                  + reluf(acc[m][n][3] + bb.w) * ww.w;
        }
    }
    #pragma unroll
    for (int n = 0; n < 4; ++n) {
        s[n] += __shfl_xor(s[n], 16, 64);
        s[n] += __shfl_xor(s[n], 32, 64);
        if (l16 == 0) atomicAdd(&o_s[n * 16 + l15], s[n]);
    }
    __syncthreads();
    if (tid < 64) {
        int row = row0 + tid;
        if (row < N) out[row] = o_s[tid] + b2[0];
    }
}

__global__ __launch_bounds__(256) void sentinel_kernel(float* out, int n, float val)
{
    int i = blockIdx.x * 256 + threadIdx.x;
    if (i < n) out[i] = (i == 0) ? val : 0.f;
}

// ---------------------------------------------------------------------------
static void build_csr(const int* src, const int* dst, int E, int N,
                      int* deg, int* start, int* cursor, int* eidx, int* bsum,
                      hipStream_t stream)
{
    const dim3 blk(256);
    hipMemsetAsync(deg, 0, (size_t)N * sizeof(int), stream);
    hist_kernel<<<dim3((E + 255) / 256), blk, 0, stream>>>(dst, deg, E);
    int B = (N + 1023) / 1024;
    scan_blocks_kernel<<<dim3(B), blk, 0, stream>>>(deg, start, bsum, N);
    scan_top_kernel<<<dim3(1), blk, 0, stream>>>(bsum, B);
    scan_add_kernel<<<dim3((N + 255) / 256), blk, 0, stream>>>(start, cursor, bsum, N);
    fill_kernel<<<dim3((E + 255) / 256), blk, 0, stream>>>(src, dst, cursor, eidx, E);
}

extern "C" void kernel_launch(void* const* d_in, const int* in_sizes, int n_in,
                              void* d_out, int out_size, void* d_ws, size_t ws_size,
                              hipStream_t stream)
{
    const float* x_col  = (const float*)d_in[0];
    const float* x_filt = (const float*)d_in[1];
    const float* x_pred = (const float*)d_in[2];
    const float* x_scan = (const float*)d_in[3];
    const float* x_join = (const float*)d_in[4];
    const float* x_enc  = (const float*)d_in[5];
    const float* W_enc  = (const float*)d_in[6];
    const float* b_enc  = (const float*)d_in[7];
    const float* W1t    = (const float*)d_in[8];
    const float* b1t    = (const float*)d_in[9];
    const float* W2t    = (const float*)d_in[10];
    const float* b2t    = (const float*)d_in[11];
    const float* Wf1    = (const float*)d_in[12];
    const float* bf1    = (const float*)d_in[13];
    const float* Wf2    = (const float*)d_in[14];
    const float* bf2    = (const float*)d_in[15];
    const int* src_cf = (const int*)d_in[16];
    const int* dst_cf = (const int*)d_in[17];
    const int* src_fp = (const int*)d_in[18];
    const int* dst_fp = (const int*)d_in[19];
    const int* src_ps = (const int*)d_in[20];
    const int* dst_ps = (const int*)d_in[21];
    const int* src_sj = (const int*)d_in[22];
    const int* dst_sj = (const int*)d_in[23];
    const int* src_je = (const int*)d_in[24];
    const int* dst_je = (const int*)d_in[25];

    const int N_COL  = in_sizes[0] / FIN;
    const int N_FILT = in_sizes[1] / FIN;
    const int N_PRED = in_sizes[2] / FIN;
    const int N_SCAN = in_sizes[3] / FIN;
    const int N_JOIN = in_sizes[4] / FIN;
    const int N_ENC  = in_sizes[5] / FIN;
    const int E_CF = in_sizes[16];
    const int E_FP = in_sizes[18];
    const int E_PS = in_sizes[20];
    const int E_SJ = in_sizes[22];
    const int E_JE = in_sizes[24];

    // ---- workspace layout ----
    size_t Mf = 0;
    {
        size_t c;
        c = (size_t)N_FILT * HDIM; if (c > Mf) Mf = c;
        c = (size_t)N_PRED * HDIM; if (c > Mf) Mf = c;
        c = (size_t)N_SCAN * HDIM; if (c > Mf) Mf = c;
        c = (size_t)N_JOIN * HDIM; if (c > Mf) Mf = c;
        c = (size_t)N_ENC  * HDIM; if (c > Mf) Mf = c;
    }
    size_t Hf = (size_t)N_COL * HDIM;
    { size_t c = (size_t)(N_FILT + N_PRED) * HDIM; if (c > Hf) Hf = c; }
    { size_t c = (size_t)(N_SCAN + N_JOIN + N_ENC + N_PRED) * HDIM; if (c > Hf) Hf = c; }

    int maxN = N_FILT;
    if (N_PRED > maxN) maxN = N_PRED;
    if (N_SCAN > maxN) maxN = N_SCAN;
    if (N_JOIN > maxN) maxN = N_JOIN;
    if (N_ENC  > maxN) maxN = N_ENC;
    int maxE = E_CF;
    if (E_FP > maxE) maxE = E_FP;
    if (E_PS > maxE) maxE = E_PS;
    if (E_SJ > maxE) maxE = E_SJ;
    if (E_JE > maxE) maxE = E_JE;

    const int W1P_TOT = 5 * 2 * HDIM * HDIM;   // 163840 bf16
    const int W2P_TOT = 5 * HDIM * HDIM;       //  81920 bf16
    const int WEP_TOT = 6 * FIN * HDIM;        //  24576 bf16
    const int WFP_TOT = HDIM * HDIM;           //  16384 bf16

    size_t msgB  = ((Mf * 2) + 255) & ~(size_t)255;
    size_t hB    = ((Hf * 2) + 255) & ~(size_t)255;
    size_t intB  = (((size_t)maxN * 4) + 255) & ~(size_t)255;
    size_t eidxB = (((size_t)maxE * 4) + 255) & ~(size_t)255;
    size_t wpB   = (((size_t)(W1P_TOT + W2P_TOT + WEP_TOT + WFP_TOT) * 2) + 255) & ~(size_t)255;
    size_t need  = msgB + hB + 3 * intB + eidxB + wpB + 8192;

    if (!d_ws || ws_size < need) {
        float val = 1.0e6f + (float)(ws_size >> 20);
        sentinel_kernel<<<dim3((out_size + 255) / 256), dim3(256), 0, stream>>>(
            (float*)d_out, out_size, val);
        return;
    }

    char* base = (char*)d_ws;
    bf16t* msg  = (bf16t*)base;                       base += msgB;
    bf16t* H    = (bf16t*)base;                       base += hB;
    int* deg    = (int*)base;                         base += intB;
    int* start  = (int*)base;                         base += intB;
    int* cursor = (int*)base;                         base += intB;
    int* eidx   = (int*)base;                         base += eidxB;
    bf16t* W1P  = (bf16t*)base;                       base += (size_t)W1P_TOT * 2;
    bf16t* W2P  = (bf16t*)base;                       base += (size_t)W2P_TOT * 2;
    bf16t* WEP  = (bf16t*)base;                       base += (size_t)WEP_TOT * 2;
    bf16t* WFP  = (bf16t*)base;                       base += (size_t)WFP_TOT * 2;
    int* bsum   = (int*)(((size_t)base + 255) & ~(size_t)255);

    bf16t* h_col  = H;                                 // dead after gather0
    bf16t* h_filt = H;
    bf16t* h_pred = H + (size_t)N_FILT * HDIM;
    bf16t* h_scan = H;                                 // h_filt dead by then
    bf16t* h_join = H + (size_t)N_SCAN * HDIM;
    bf16t* h_enc  = H + (size_t)(N_SCAN + N_JOIN) * HDIM;

    const dim3 blk(256);

    // ---- weight repacks (bf16, MFMA fragment order) ----
    pack_w1_kernel<<<dim3((W1P_TOT + 255) / 256), blk, 0, stream>>>(W1t, W1P, W1P_TOT);
    pack_w2_kernel<<<dim3((W2P_TOT + 255) / 256), blk, 0, stream>>>(W2t, W2P, W2P_TOT);
    pack_we_kernel<<<dim3((WEP_TOT + 255) / 256), blk, 0, stream>>>(W_enc, WEP, WEP_TOT);
    pack_w2_kernel<<<dim3((WFP_TOT + 255) / 256), blk, 0, stream>>>(Wf1, WFP, WFP_TOT);

    // ---- level 0: column -> filter ----
    build_csr(src_cf, dst_cf, E_CF, N_FILT, deg, start, cursor, eidx, bsum, stream);
    enc_mfma_kernel<<<dim3((N_COL + 63) / 64), blk, 0, stream>>>(
        x_col, WEP, b_enc, h_col, N_COL);
    gather_kernel<<<dim3((N_FILT + 7) / 8), blk, 0, stream>>>(
        h_col, eidx, start, deg, msg, N_FILT);
    enc_mfma_kernel<<<dim3((N_FILT + 63) / 64), blk, 0, stream>>>(   // overwrites h_col region
        x_filt, WEP + 1 * FIN * HDIM, b_enc + 1 * HDIM, h_filt, N_FILT);
    combine_mfma_kernel<<<dim3((N_FILT + 63) / 64), blk, 0, stream>>>(
        h_filt, msg, W1P, b1t, W2P, b2t, N_FILT);

    // ---- level 1: filter -> pred ----
    build_csr(src_fp, dst_fp, E_FP, N_PRED, deg, start, cursor, eidx, bsum, stream);
    gather_kernel<<<dim3((N_PRED + 7) / 8), blk, 0, stream>>>(
        h_filt, eidx, start, deg, msg, N_PRED);
    enc_mfma_kernel<<<dim3((N_PRED + 63) / 64), blk, 0, stream>>>(
        x_pred, WEP + 2 * FIN * HDIM, b_enc + 2 * HDIM, h_pred, N_PRED);
    combine_mfma_kernel<<<dim3((N_PRED + 63) / 64), blk, 0, stream>>>(
        h_pred, msg, W1P + 1 * 2 * HDIM * HDIM, b1t + 1 * HDIM,
        W2P + 1 * HDIM * HDIM, b2t + 1 * HDIM, N_PRED);

    // ---- level 2: pred -> scan ----
    build_csr(src_ps, dst_ps, E_PS, N_SCAN, deg, start, cursor, eidx, bsum, stream);
    gather_kernel<<<dim3((N_SCAN + 7) / 8), blk, 0, stream>>>(
        h_pred, eidx, start, deg, msg, N_SCAN);
    enc_mfma_kernel<<<dim3((N_SCAN + 63) / 64), blk, 0, stream>>>(
        x_scan, WEP + 3 * FIN * HDIM, b_enc + 3 * HDIM, h_scan, N_SCAN);
    combine_mfma_kernel<<<dim3((N_SCAN + 63) / 64), blk, 0, stream>>>(
        h_scan, msg, W1P + 2 * 2 * HDIM * HDIM, b1t + 2 * HDIM,
        W2P + 2 * HDIM * HDIM, b2t + 2 * HDIM, N_SCAN);

    // ---- level 3: scan -> join ----
    build_csr(src_sj, dst_sj, E_SJ, N_JOIN, deg, start, cursor, eidx, bsum, stream);
    gather_kernel<<<dim3((N_JOIN + 7) / 8), blk, 0, stream>>>(
        h_scan, eidx, start, deg, msg, N_JOIN);
    enc_mfma_kernel<<<dim3((N_JOIN + 63) / 64), blk, 0, stream>>>(
        x_join, WEP + 4 * FIN * HDIM, b_enc + 4 * HDIM, h_join, N_JOIN);
    combine_mfma_kernel<<<dim3((N_JOIN + 63) / 64), blk, 0, stream>>>(
        h_join, msg, W1P + 3 * 2 * HDIM * HDIM, b1t + 3 * HDIM,
        W2P + 3 * HDIM * HDIM, b2t + 3 * HDIM, N_JOIN);

    // ---- level 4: join -> encode ----
    build_csr(src_je, dst_je, E_JE, N_ENC, deg, start, cursor, eidx, bsum, stream);
    gather_kernel<<<dim3((N_ENC + 7) / 8), blk, 0, stream>>>(
        h_join, eidx, start, deg, msg, N_ENC);
    enc_mfma_kernel<<<dim3((N_ENC + 63) / 64), blk, 0, stream>>>(
        x_enc, WEP + 5 * FIN * HDIM, b_enc + 5 * HDIM, h_enc, N_ENC);
    combine_mfma_kernel<<<dim3((N_ENC + 63) / 64), blk, 0, stream>>>(
        h_enc, msg, W1P + 4 * 2 * HDIM * HDIM, b1t + 4 * HDIM,
        W2P + 4 * HDIM * HDIM, b2t + 4 * HDIM, N_ENC);

    // ---- fused final MLP + projection ----
    finale_kernel<<<dim3((N_ENC + 63) / 64), blk, 0, stream>>>(
        h_enc, WFP, bf1, Wf2, bf2, (float*)d_out, N_ENC);
}